// Round 5
// baseline (428.395 us; speedup 1.0000x reference)
//
#include <hip/hip_runtime.h>
#include <hip/hip_bf16.h>

#define NN 50000
#define EE 1000000
#define FIN 512
#define HIDDEN 128
#define NH 8
#define DH 16
#define NOUT 3
#define NBUCK 196   // ceil(NN/256) coarse dst buckets
#define EPB 8192    // edges per block in scatterA
#define NBLKA ((EE + EPB - 1) / EPB)

typedef unsigned short u16;
typedef unsigned int u32;
typedef __attribute__((ext_vector_type(8))) short short8;
typedef __attribute__((ext_vector_type(4))) float f32x4;

__device__ __forceinline__ float b2f(u16 b) { return __uint_as_float(((u32)b) << 16); }
__device__ __forceinline__ u16 f2b(float f) { return (u16)(__float_as_uint(f) >> 16); }
__device__ __forceinline__ u16 f2b_rne(float f) {
    u32 u = __float_as_uint(f);
    return (u16)((u + 0x7FFFu + ((u >> 16) & 1u)) >> 16);
}

__device__ __forceinline__ void gload16(const u16* g, u16* l) {
    __builtin_amdgcn_global_load_lds(
        (const __attribute__((address_space(1))) unsigned int*)(g),
        (__attribute__((address_space(3))) unsigned int*)(l), 16, 0, 0);
}

// Converted-weight layout (fp32), offsets within wconv:
#define W_WP   0
#define W_BP   65536
#define W_AS0  65664
#define W_AD0  65792
#define W_AS1  65920
#define W_AD1  66048
#define W_WK   66176
#define W_BK   82560
#define W_Q    82688
#define W_WL   82816
#define W_BL   83200
#define W_TOT  83203

// ---------------- Dtype detection ----------------
__global__ void k_detect(const void* __restrict__ x, int* __restrict__ flag)
{
    const u16* xb = (const u16*)x;
    int t = threadIdx.x;
    int insane = 0;
    #pragma unroll
    for (int i = 0; i < 16; ++i) {
        int idx = ((t * 16 + i) * 131) * 2;
        float v = b2f(xb[idx]);
        float a = fabsf(v);
        bool sane = (a == 0.0f) || (a >= 1e-8f && a <= 1e4f);
        insane += sane ? 0 : 1;
    }
    __shared__ int red[256];
    red[t] = insane;
    __syncthreads();
    for (int s = 128; s > 0; s >>= 1) { if (t < s) red[t] += red[t + s]; __syncthreads(); }
    if (t == 0) flag[0] = (red[0] > 1024) ? 1 : 0;   // 1 = fp32 inputs, 0 = bf16
}

// ---------------- Convert all small weights to canonical fp32 ----------------
__global__ __launch_bounds__(256) void k_convert(
    const void* Wp, const void* bp, const void* as0, const void* ad0,
    const void* as1, const void* ad1, const void* Wk, const void* bk,
    const void* q, const void* Wl, const void* bl,
    const int* __restrict__ flag, float* __restrict__ W)
{
    int i = blockIdx.x * 256 + threadIdx.x;
    if (i >= W_TOT) return;
    const void* src; int off;
    if      (i < W_BP)  { src = Wp;  off = i; }
    else if (i < W_AS0) { src = bp;  off = i - W_BP; }
    else if (i < W_AD0) { src = as0; off = i - W_AS0; }
    else if (i < W_AS1) { src = ad0; off = i - W_AD0; }
    else if (i < W_AD1) { src = as1; off = i - W_AS1; }
    else if (i < W_WK)  { src = ad1; off = i - W_AD1; }
    else if (i < W_BK)  { src = Wk;  off = i - W_WK; }
    else if (i < W_Q)   { src = bk;  off = i - W_BK; }
    else if (i < W_WL)  { src = q;   off = i - W_Q; }
    else if (i < W_BL)  { src = Wl;  off = i - W_WL; }
    else                { src = bl;  off = i - W_BL; }
    float v = flag[0] ? ((const float*)src)[off] : b2f(((const u16*)src)[off]);
    W[i] = v;
}

// ---------------- Prep: W_proj^T (hi/lo) and Wk^T (hi only) as bf16 ----------------
#define PREPN (FIN*HIDDEN + HIDDEN*HIDDEN)   // 65536 + 16384
__global__ __launch_bounds__(256) void k_prepw(
    const float* __restrict__ Wpf, const float* __restrict__ Wkf,
    u16* __restrict__ WhiT, u16* __restrict__ WloT, u16* __restrict__ WkThi)
{
    int idx = blockIdx.x*256 + threadIdx.x;
    if (idx >= PREPN) return;
    if (idx < FIN*HIDDEN) {
        int k = idx >> 7, n = idx & 127;
        float w = Wpf[idx];
        u32 hb = __float_as_uint(w) & 0xFFFF0000u;
        WhiT[(size_t)n*FIN + k] = (u16)(hb >> 16);
        WloT[(size_t)n*FIN + k] = f2b(w - __uint_as_float(hb));
    } else {
        int i = idx - FIN*HIDDEN;
        int k = i >> 7, h = i & 127;
        WkThi[(size_t)h*HIDDEN + k] = f2b_rne(Wkf[i]);
    }
}

// ================= Projection, fp32-input fast path =================
__global__ __launch_bounds__(256) void k_projm_f32(
    const void* __restrict__ xv, const u16* __restrict__ WhiT,
    const u16* __restrict__ WloT, const float* __restrict__ bpf,
    const int* __restrict__ flag, u16* __restrict__ xpb)
{
    if (!flag[0]) return;                     // bf16 inputs -> k_projm_bf16
    __shared__ u16 lds[2][16384];             // 64 KB
    const int t = threadIdx.x;
    const int lane = t & 63;
    const int wid = t >> 6;
    const int m16 = lane & 15;
    const int quad = lane >> 4;
    const int wr = wid >> 1, wc = wid & 1;
    const int blockRow = blockIdx.x * 128;
    const float* xf = (const float*)xv;

    const int srow = t >> 1;
    const int shalf = t & 1;
    int gxrow = blockRow + srow; if (gxrow >= NN) gxrow = NN - 1;
    const float* xr = xf + (size_t)gxrow * FIN + shalf * 16;
    const int ssw = (srow >> 1) & 3;
    const int aw0 = srow*32 + ((shalf*2)     ^ ssw) * 8;
    const int aw1 = srow*32 + ((shalf*2 + 1) ^ ssw) * 8;

    int bp0 = t, bp1 = t + 256;
    int br0 = bp0 >> 2, br1 = bp1 >> 2;
    int bc0 = (bp0 & 3) ^ ((br0 >> 1) & 3);
    int bc1 = (bp1 & 3) ^ ((br1 >> 1) & 3);
    const u16* srcBh0 = WhiT + (size_t)br0 * FIN + bc0 * 8;
    const u16* srcBh1 = WhiT + (size_t)br1 * FIN + bc1 * 8;
    const u16* srcBl0 = WloT + (size_t)br0 * FIN + bc0 * 8;
    const u16* srcBl1 = WloT + (size_t)br1 * FIN + bc1 * 8;
    const int dB0 = bp0 * 8, dB1 = bp1 * 8;

    int aoff[4], boff[4];
    #pragma unroll
    for (int mt = 0; mt < 4; ++mt) {
        int r = wr*64 + mt*16 + m16;
        aoff[mt] = r*32 + ((quad ^ ((r >> 1) & 3)) << 3);
    }
    #pragma unroll
    for (int nt = 0; nt < 4; ++nt) {
        int r = wc*64 + nt*16 + m16;
        boff[nt] = r*32 + ((quad ^ ((r >> 1) & 3)) << 3);
    }

    f32x4 acc[4][4];
    #pragma unroll
    for (int i = 0; i < 4; ++i)
        #pragma unroll
        for (int j = 0; j < 4; ++j) acc[i][j] = (f32x4)(0.f);

    u16* Lc = lds[0];
    u16* Ln = lds[1];

    {
        float4 v0 = *(const float4*)(xr);
        float4 v1 = *(const float4*)(xr + 4);
        float4 v2 = *(const float4*)(xr + 8);
        float4 v3 = *(const float4*)(xr + 12);
        gload16(srcBh0, Lc + 8192  + dB0);
        gload16(srcBh1, Lc + 8192  + dB1);
        gload16(srcBl0, Lc + 12288 + dB0);
        gload16(srcBl1, Lc + 12288 + dB1);
        float xs[16] = {v0.x,v0.y,v0.z,v0.w, v1.x,v1.y,v1.z,v1.w,
                        v2.x,v2.y,v2.z,v2.w, v3.x,v3.y,v3.z,v3.w};
        short8 h0, h1, l0, l1;
        #pragma unroll
        for (int j = 0; j < 8; ++j) {
            u32 u = __float_as_uint(xs[j]);   u32 hb = u & 0xFFFF0000u;
            h0[j] = (short)(hb >> 16); l0[j] = (short)f2b(xs[j] - __uint_as_float(hb));
            u32 u2 = __float_as_uint(xs[8+j]); u32 hb2 = u2 & 0xFFFF0000u;
            h1[j] = (short)(hb2 >> 16); l1[j] = (short)f2b(xs[8+j] - __uint_as_float(hb2));
        }
        *(short8*)(Lc + aw0) = h0;
        *(short8*)(Lc + aw1) = h1;
        *(short8*)(Lc + 4096 + aw0) = l0;
        *(short8*)(Lc + 4096 + aw1) = l1;
    }
    __syncthreads();

    #pragma unroll 1
    for (int ks = 0; ks < 16; ++ks) {
        const int kt = (ks + 1) * 32;
        float4 v0, v1, v2, v3;
        if (ks < 15) {
            v0 = *(const float4*)(xr + kt);
            v1 = *(const float4*)(xr + kt + 4);
            v2 = *(const float4*)(xr + kt + 8);
            v3 = *(const float4*)(xr + kt + 12);
            gload16(srcBh0 + kt, Ln + 8192  + dB0);
            gload16(srcBh1 + kt, Ln + 8192  + dB1);
            gload16(srcBl0 + kt, Ln + 12288 + dB0);
            gload16(srcBl1 + kt, Ln + 12288 + dB1);
        }
        short8 bh[4], bl[4];
        #pragma unroll
        for (int nt = 0; nt < 4; ++nt) {
            bh[nt] = *(const short8*)(Lc + 8192  + boff[nt]);
            bl[nt] = *(const short8*)(Lc + 12288 + boff[nt]);
        }
        #pragma unroll
        for (int mt = 0; mt < 4; ++mt) {
            short8 ah = *(const short8*)(Lc + aoff[mt]);
            short8 al = *(const short8*)(Lc + 4096 + aoff[mt]);
            #pragma unroll
            for (int nt = 0; nt < 4; ++nt) {
                acc[mt][nt] = __builtin_amdgcn_mfma_f32_16x16x32_bf16(ah, bh[nt], acc[mt][nt], 0,0,0);
                acc[mt][nt] = __builtin_amdgcn_mfma_f32_16x16x32_bf16(ah, bl[nt], acc[mt][nt], 0,0,0);
                acc[mt][nt] = __builtin_amdgcn_mfma_f32_16x16x32_bf16(al, bh[nt], acc[mt][nt], 0,0,0);
            }
        }
        if (ks < 15) {
            float xs[16] = {v0.x,v0.y,v0.z,v0.w, v1.x,v1.y,v1.z,v1.w,
                            v2.x,v2.y,v2.z,v2.w, v3.x,v3.y,v3.z,v3.w};
            short8 h0, h1, l0, l1;
            #pragma unroll
            for (int j = 0; j < 8; ++j) {
                u32 u = __float_as_uint(xs[j]);   u32 hb = u & 0xFFFF0000u;
                h0[j] = (short)(hb >> 16); l0[j] = (short)f2b(xs[j] - __uint_as_float(hb));
                u32 u2 = __float_as_uint(xs[8+j]); u32 hb2 = u2 & 0xFFFF0000u;
                h1[j] = (short)(hb2 >> 16); l1[j] = (short)f2b(xs[8+j] - __uint_as_float(hb2));
            }
            *(short8*)(Ln + aw0) = h0;
            *(short8*)(Ln + aw1) = h1;
            *(short8*)(Ln + 4096 + aw0) = l0;
            *(short8*)(Ln + 4096 + aw1) = l1;
        }
        __syncthreads();
        u16* tmp = Lc; Lc = Ln; Ln = tmp;
    }

    #pragma unroll
    for (int nt = 0; nt < 4; ++nt) {
        int col = wc*64 + nt*16 + m16;
        float bias = bpf[col];
        #pragma unroll
        for (int mt = 0; mt < 4; ++mt) {
            int orow0 = blockRow + wr*64 + mt*16 + quad*4;
            #pragma unroll
            for (int r = 0; r < 4; ++r) {
                int orow = orow0 + r;
                if (orow < NN) xpb[(size_t)orow*HIDDEN + col] = f2b_rne(acc[mt][nt][r] + bias);
            }
        }
    }
}

// ---------------- Projection (bf16-input path): 128x128 tile LDS-staged MFMA GEMM ----
__global__ __launch_bounds__(256) void k_projm_bf16(
    const void* __restrict__ x, const u16* __restrict__ WhiT,
    const u16* __restrict__ WloT, const float* __restrict__ bpf,
    const int* __restrict__ flag, u16* __restrict__ xpb)
{
    if (flag[0]) return;                      // fp32 inputs handled by k_projm_f32
    __shared__ u16 lds[2][12288];             // 48 KB total
    const int t = threadIdx.x;
    const int lane = t & 63;
    const int wid = t >> 6;
    const int m16 = lane & 15;
    const int quad = lane >> 4;
    const int wr = wid >> 1, wc = wid & 1;
    const int blockRow = blockIdx.x * 128;
    const u16* xb = (const u16*)x;

    const int r0 = t >> 2,         c0 = (t & 3) * 8;
    const int r1 = (t + 256) >> 2, c1 = ((t + 256) & 3) * 8;
    int g0 = blockRow + r0; if (g0 >= NN) g0 = NN - 1;
    int g1 = blockRow + r1; if (g1 >= NN) g1 = NN - 1;
    const u16* srcA0  = xb   + (size_t)g0 * FIN + c0;
    const u16* srcA1  = xb   + (size_t)g1 * FIN + c1;
    const u16* srcBh0 = WhiT + (size_t)r0 * FIN + c0;
    const u16* srcBh1 = WhiT + (size_t)r1 * FIN + c1;
    const u16* srcBl0 = WloT + (size_t)r0 * FIN + c0;
    const u16* srcBl1 = WloT + (size_t)r1 * FIN + c1;

#define PSTAGE(buf, kt) do { \
        gload16(srcA0  + (kt), &lds[buf][t*8]); \
        gload16(srcA1  + (kt), &lds[buf][2048 + t*8]); \
        gload16(srcBh0 + (kt), &lds[buf][4096 + t*8]); \
        gload16(srcBh1 + (kt), &lds[buf][6144 + t*8]); \
        gload16(srcBl0 + (kt), &lds[buf][8192 + t*8]); \
        gload16(srcBl1 + (kt), &lds[buf][10240 + t*8]); \
    } while (0)

    f32x4 acc[4][4];
    #pragma unroll
    for (int i = 0; i < 4; ++i)
        #pragma unroll
        for (int j = 0; j < 4; ++j) acc[i][j] = (f32x4)(0.f);

    PSTAGE(0, 0);
    __syncthreads();
    int cur = 0;
    for (int ks = 0; ks < 16; ++ks) {
        if (ks < 15) {
            if (cur) PSTAGE(0, (ks + 1) * 32);
            else     PSTAGE(1, (ks + 1) * 32);
        }
        const u16* L = lds[cur];
        short8 a[4], bh[4], bl[4];
        #pragma unroll
        for (int mt = 0; mt < 4; ++mt)
            a[mt] = *(const short8*)&L[(wr*64 + mt*16 + m16)*32 + quad*8];
        #pragma unroll
        for (int nt = 0; nt < 4; ++nt) {
            bh[nt] = *(const short8*)&L[4096 + (wc*64 + nt*16 + m16)*32 + quad*8];
            bl[nt] = *(const short8*)&L[8192 + (wc*64 + nt*16 + m16)*32 + quad*8];
        }
        #pragma unroll
        for (int mt = 0; mt < 4; ++mt)
            #pragma unroll
            for (int nt = 0; nt < 4; ++nt) {
                acc[mt][nt] = __builtin_amdgcn_mfma_f32_16x16x32_bf16(a[mt], bh[nt], acc[mt][nt], 0,0,0);
                acc[mt][nt] = __builtin_amdgcn_mfma_f32_16x16x32_bf16(a[mt], bl[nt], acc[mt][nt], 0,0,0);
            }
        __syncthreads();
        cur ^= 1;
    }
#undef PSTAGE

    #pragma unroll
    for (int nt = 0; nt < 4; ++nt) {
        int col = wc*64 + nt*16 + m16;
        float bias = bpf[col];
        #pragma unroll
        for (int mt = 0; mt < 4; ++mt) {
            int orow0 = blockRow + wr*64 + mt*16 + quad*4;
            #pragma unroll
            for (int r = 0; r < 4; ++r) {
                int orow = orow0 + r;
                if (orow < NN) xpb[(size_t)orow*HIDDEN + col] = f2b_rne(acc[mt][nt][r] + bias);
            }
        }
    }
}

// ---------------- Attention coefficients (bf16 xpb input) ----------------
__global__ __launch_bounds__(256) void k_attcoef(
    const u16* __restrict__ xpb, const float* __restrict__ watt,
    float* __restrict__ o_as0, float* __restrict__ o_ad0,
    float* __restrict__ o_as1, float* __restrict__ o_ad1)
{
    __shared__ float s0[128], d0[128], s1[128], d1[128];
    const int t = threadIdx.x;
    if (t < 128) { s0[t]=watt[t]; d0[t]=watt[128+t]; s1[t]=watt[256+t]; d1[t]=watt[384+t]; }
    __syncthreads();
    int tid = blockIdx.x*256 + t;               // n*8 + h
    if (tid >= NN*NH) return;
    int h = tid & 7;
    const u32* px = (const u32*)(xpb + (size_t)tid * DH);
    float xv[16];
    #pragma unroll
    for (int i=0;i<8;++i){ u32 v=px[i]; xv[i*2]=b2f((u16)(v&0xFFFF)); xv[i*2+1]=b2f((u16)(v>>16)); }
    float r0=0.f,r1=0.f,r2=0.f,r3=0.f;
    #pragma unroll
    for (int d=0; d<16; ++d) {
        float xvd = xv[d];
        r0 += xvd*s0[h*16+d]; r1 += xvd*d0[h*16+d];
        r2 += xvd*s1[h*16+d]; r3 += xvd*d1[h*16+d];
    }
    o_as0[tid]=r0; o_ad0[tid]=r1; o_as1[tid]=r2; o_ad1[tid]=r3;
}

// ---------------- Bucket histogram: LDS-aggregated, 196 coarse buckets ----------------
__global__ __launch_bounds__(256) void k_bhist(
    const int* __restrict__ ei0, const int* __restrict__ ei1, int* __restrict__ bcnt)
{
    const int mp = blockIdx.y;
    const int* ei = mp ? ei1 : ei0;
    __shared__ int h[NBUCK];
    const int t = threadIdx.x;
    for (int b = t; b < NBUCK; b += 256) h[b] = 0;
    __syncthreads();
    const int e0 = blockIdx.x * EPB;
    #pragma unroll
    for (int i = 0; i < EPB/256; ++i) {
        int idx = e0 + i*256 + t;
        if (idx < EE) atomicAdd(&h[ei[EE + idx] >> 8], 1);
    }
    __syncthreads();
    for (int b = t; b < NBUCK; b += 256)
        if (h[b]) atomicAdd(&bcnt[mp*256 + b], h[b]);
}

// ---------------- Bucket scan: bucket starts -> bstart + curA init ----------------
__global__ __launch_bounds__(512) void k_bscan(
    const int* __restrict__ bcnt, int* __restrict__ bstart, int* __restrict__ curA)
{
    __shared__ int s[2][256];
    const int mp = threadIdx.x >> 8;
    const int t = threadIdx.x & 255;
    int v = (t < NBUCK) ? bcnt[mp*256 + t] : 0;
    s[mp][t] = v;
    __syncthreads();
    for (int off = 1; off < 256; off <<= 1) {
        int u = (t >= off) ? s[mp][t - off] : 0;
        __syncthreads();
        s[mp][t] += u;
        __syncthreads();
    }
    int excl = s[mp][t] - v;
    if (t < NBUCK) {
        bstart[mp*200 + t] = excl;
        curA[(mp*256 + t)*16] = excl;
    }
    if (t == NBUCK - 1) bstart[mp*200 + NBUCK] = excl + v;
}

// ---------------- Scatter pass A: reserve-segment coarse binning ----------------
__global__ __launch_bounds__(256) void k_scatterA(
    const int* __restrict__ ei0, const int* __restrict__ ei1,
    int* __restrict__ curA, int2* __restrict__ tmp0, int2* __restrict__ tmp1)
{
    const int mp = blockIdx.y;
    const int* ei = mp ? ei1 : ei0;
    int2* tmp = mp ? tmp1 : tmp0;
    __shared__ int hist[NBUCK];
    __shared__ int seg[NBUCK];
    __shared__ int cnt[NBUCK];
    const int t = threadIdx.x;
    for (int b = t; b < NBUCK; b += 256) hist[b] = 0;
    __syncthreads();
    const int e0 = blockIdx.x * EPB;
    #pragma unroll
    for (int i = 0; i < EPB/256; ++i) {
        int idx = e0 + i*256 + t;
        if (idx < EE) atomicAdd(&hist[ei[EE + idx] >> 8], 1);
    }
    __syncthreads();
    for (int b = t; b < NBUCK; b += 256) {
        int h = hist[b];
        seg[b] = h ? atomicAdd(&curA[(mp*256 + b)*16], h) : 0;
        cnt[b] = 0;
    }
    __syncthreads();
    #pragma unroll
    for (int i = 0; i < EPB/256; ++i) {
        int idx = e0 + i*256 + t;
        if (idx < EE) {
            int s = ei[idx], d = ei[EE + idx];
            int b = d >> 8;
            int pos = seg[b] + atomicAdd(&cnt[b], 1);
            tmp[pos] = make_int2(s, d);
        }
    }
}

// ---------------- Scatter pass B: per-bucket LDS count+scan -> base[] and srt ----------------
__global__ __launch_bounds__(256) void k_scatterB(
    const int2* __restrict__ tmp0, const int2* __restrict__ tmp1,
    const int* __restrict__ bstart,
    int* __restrict__ base0, int* __restrict__ base1,
    int* __restrict__ srt0, int* __restrict__ srt1)
{
    const int b = blockIdx.x;
    const int mp = blockIdx.y;
    const int2* tmp = mp ? tmp1 : tmp0;
    int* base = mp ? base1 : base0;
    int* srt  = mp ? srt1 : srt0;
    const int lo = bstart[mp*200 + b];
    const int hi = bstart[mp*200 + b + 1];
    __shared__ int lcnt[256];   // per-node counts, then placement counters
    __shared__ int loff[256];   // scan workspace -> per-node exclusive offsets
    const int t = threadIdx.x;
    lcnt[t] = 0;
    __syncthreads();
    for (int i = lo + t; i < hi; i += 256)
        atomicAdd(&lcnt[tmp[i].y & 255], 1);
    __syncthreads();
    int v = lcnt[t];
    loff[t] = v;
    __syncthreads();
    for (int off = 1; off < 256; off <<= 1) {
        int u = (t >= off) ? loff[t - off] : 0;
        __syncthreads();
        loff[t] += u;
        __syncthreads();
    }
    int excl = loff[t] - v;
    int node = (b << 8) + t;
    if (node < NN) base[node] = lo + excl;
    if (b == NBUCK - 1 && t == 0) base[NN] = EE;
    __syncthreads();
    loff[t] = excl;             // stable per-node start
    lcnt[t] = 0;                // reuse as placement counter
    __syncthreads();
    for (int i = lo + t; i < hi; i += 256) {
        int2 sd = tmp[i];
        int local = sd.y & 255;
        int pos = lo + loff[local] + atomicAdd(&lcnt[local], 1);
        srt[pos] = sd.x;
    }
}

// ---------------- Gather v3: 8 edges/iter, software-pipelined 2-chunk ping-pong.
// Weights computed 8x8 (edge x head) in one shot, redistributed via ds_bpermute;
// row bases via readlane->SGPR. Chunk i+8's srt/asr/rows staged while chunk i
// computes, so every load gets ~1 chunk of latency cover (T14). ----------------
__global__ __launch_bounds__(256) void k_gather(
    const int* __restrict__ srt0, const int* __restrict__ srt1,
    const int* __restrict__ base0, const int* __restrict__ base1,
    const float* __restrict__ as0, const float* __restrict__ ad0,
    const float* __restrict__ as1, const float* __restrict__ ad1,
    const u16* __restrict__ xpb, u16* __restrict__ obf0, u16* __restrict__ obf1)
{
    const int t = threadIdx.x;
    const int wid = blockIdx.x*4 + (t >> 6);
    if (wid >= NN) return;
    const int lane = t & 63;
    const int hc = lane & 7;        // head in weight-compute phase
    const int eg = lane >> 3;       // edge slot in chunk (weight phase)
    const int mp = blockIdx.y;
    const int*  srt  = mp ? srt1  : srt0;
    const int*  base = mp ? base1 : base0;
    const float* asr = mp ? as1 : as0;
    const float* ads = mp ? ad1 : ad0;
    u16* obf = mp ? obf1 : obf0;
    const u32* xw = (const u32*)xpb;     // 64 u32 per row

    const int b = base[wid], e = base[wid + 1];
    const float adv = ads[wid*NH + hc];          // dst coefficient, head hc
    // precomputed bpermute addresses: weight src lane = k2*8 + (lane>>3)
    const int bpb = (lane >> 3) << 2;
    const int bpa0 = bpb;           const int bpa1 = bpb + 32;
    const int bpa2 = bpb + 64;      const int bpa3 = bpb + 96;
    const int bpa4 = bpb + 128;     const int bpa5 = bpb + 160;
    const int bpa6 = bpb + 192;     const int bpa7 = bpb + 224;
    float accx = 0.f, accy = 0.f, den = 0.f;

#define GSTAGE(I, AV, R0,R1,R2,R3,R4,R5,R6,R7) do { \
        int _il = (I) + eg; int _ilc = _il < e ? _il : e - 1; \
        int _s = srt[_ilc]; \
        (AV) = asr[_s*NH + hc]; \
        const u32* _p0 = xw + ((size_t)(u32)__builtin_amdgcn_readlane(_s, 0)  << 6); \
        const u32* _p1 = xw + ((size_t)(u32)__builtin_amdgcn_readlane(_s, 8)  << 6); \
        const u32* _p2 = xw + ((size_t)(u32)__builtin_amdgcn_readlane(_s, 16) << 6); \
        const u32* _p3 = xw + ((size_t)(u32)__builtin_amdgcn_readlane(_s, 24) << 6); \
        const u32* _p4 = xw + ((size_t)(u32)__builtin_amdgcn_readlane(_s, 32) << 6); \
        const u32* _p5 = xw + ((size_t)(u32)__builtin_amdgcn_readlane(_s, 40) << 6); \
        const u32* _p6 = xw + ((size_t)(u32)__builtin_amdgcn_readlane(_s, 48) << 6); \
        const u32* _p7 = xw + ((size_t)(u32)__builtin_amdgcn_readlane(_s, 56) << 6); \
        (R0) = _p0[lane]; (R1) = _p1[lane]; (R2) = _p2[lane]; (R3) = _p3[lane]; \
        (R4) = _p4[lane]; (R5) = _p5[lane]; (R6) = _p6[lane]; (R7) = _p7[lane]; \
    } while (0)

#define GCOMP(I, AV, R0,R1,R2,R3,R4,R5,R6,R7) do { \
        float _av = (AV) + adv; \
        _av = fmaxf(_av, 0.2f*_av); \
        float _w = (((I) + eg) < e) ? __expf(_av) : 0.f; \
        int _wi = __float_as_int(_w); \
        float _wk; u32 _v; \
        _wk = __int_as_float(__builtin_amdgcn_ds_bpermute(bpa0, _wi)); _v = (R0); \
        accx = fmaf(_wk, b2f((u16)(_v & 0xFFFF)), accx); accy = fmaf(_wk, b2f((u16)(_v >> 16)), accy); den += _wk; \
        _wk = __int_as_float(__builtin_amdgcn_ds_bpermute(bpa1, _wi)); _v = (R1); \
        accx = fmaf(_wk, b2f((u16)(_v & 0xFFFF)), accx); accy = fmaf(_wk, b2f((u16)(_v >> 16)), accy); den += _wk; \
        _wk = __int_as_float(__builtin_amdgcn_ds_bpermute(bpa2, _wi)); _v = (R2); \
        accx = fmaf(_wk, b2f((u16)(_v & 0xFFFF)), accx); accy = fmaf(_wk, b2f((u16)(_v >> 16)), accy); den += _wk; \
        _wk = __int_as_float(__builtin_amdgcn_ds_bpermute(bpa3, _wi)); _v = (R3); \
        accx = fmaf(_wk, b2f((u16)(_v & 0xFFFF)), accx); accy = fmaf(_wk, b2f((u16)(_v >> 16)), accy); den += _wk; \
        _wk = __int_as_float(__builtin_amdgcn_ds_bpermute(bpa4, _wi)); _v = (R4); \
        accx = fmaf(_wk, b2f((u16)(_v & 0xFFFF)), accx); accy = fmaf(_wk, b2f((u16)(_v >> 16)), accy); den += _wk; \
        _wk = __int_as_float(__builtin_amdgcn_ds_bpermute(bpa5, _wi)); _v = (R5); \
        accx = fmaf(_wk, b2f((u16)(_v & 0xFFFF)), accx); accy = fmaf(_wk, b2f((u16)(_v >> 16)), accy); den += _wk; \
        _wk = __int_as_float(__builtin_amdgcn_ds_bpermute(bpa6, _wi)); _v = (R6); \
        accx = fmaf(_wk, b2f((u16)(_v & 0xFFFF)), accx); accy = fmaf(_wk, b2f((u16)(_v >> 16)), accy); den += _wk; \
        _wk = __int_as_float(__builtin_amdgcn_ds_bpermute(bpa7, _wi)); _v = (R7); \
        accx = fmaf(_wk, b2f((u16)(_v & 0xFFFF)), accx); accy = fmaf(_wk, b2f((u16)(_v >> 16)), accy); den += _wk; \
    } while (0)

    if (b < e) {
        float avA; u32 A0,A1,A2,A3,A4,A5,A6,A7;
        float avB; u32 B0,B1,B2,B3,B4,B5,B6,B7;
        GSTAGE(b, avA, A0,A1,A2,A3,A4,A5,A6,A7);
        int i = b;
        for (;;) {
            const bool hasB = (i + 8) < e;
            if (hasB) GSTAGE(i+8, avB, B0,B1,B2,B3,B4,B5,B6,B7);
            GCOMP(i, avA, A0,A1,A2,A3,A4,A5,A6,A7);
            if (!hasB) break;
            const bool hasC = (i + 16) < e;
            if (hasC) GSTAGE(i+16, avA, A0,A1,A2,A3,A4,A5,A6,A7);
            GCOMP(i+8, avB, B0,B1,B2,B3,B4,B5,B6,B7);
            if (!hasC) break;
            i += 16;
        }
    }
#undef GSTAGE
#undef GCOMP

    float inv = 1.f / (den + 1e-16f);
    u32 lo = f2b_rne(accx*inv), hi = f2b_rne(accy*inv);
    ((u32*)obf)[(size_t)wid*64 + lane] = (hi << 16) | lo;
}

// ---------------- Semantic scores via MFMA (bf16 obf direct A-operand) ----------------
__global__ __launch_bounds__(256) void k_semantic(
    const u16* __restrict__ obf0, const u16* __restrict__ obf1,
    const u16* __restrict__ WkThi, const float* __restrict__ bkf,
    const float* __restrict__ qf, float* __restrict__ scores)
{
    const int t = threadIdx.x;
    const int lane = t & 63;
    const int w = t >> 6;
    const int m16 = lane & 15;
    const int quad = lane >> 4;
    const int mp = blockIdx.y;
    const u16* om = mp ? obf1 : obf0;
    const int tile = blockIdx.x*4 + w;

    float partial = 0.f;
    if (tile < NN/16) {
        int row = tile*16 + m16;
        f32x4 acc[8];
        #pragma unroll
        for (int i=0;i<8;++i) acc[i] = (f32x4)(0.f);

        for (int kt = 0; kt < HIDDEN; kt += 32) {
            int kbase = kt + quad*8;
            short8 a = *(const short8*)(om + (size_t)row*HIDDEN + kbase);
            #pragma unroll
            for (int j=0;j<8;++j) a[j] = ((u16)a[j] & 0x8000u) ? (short)0 : a[j];  // relu in bf16
            #pragma unroll
            for (int nt = 0; nt < 8; ++nt) {
                int n = nt*16 + m16;
                short8 bhi = *(const short8*)(WkThi + (size_t)n*HIDDEN + kbase);
                acc[nt] = __builtin_amdgcn_mfma_f32_16x16x32_bf16(a, bhi, acc[nt], 0,0,0);
            }
        }
        #pragma unroll
        for (int nt=0; nt<8; ++nt) {
            int col = nt*16 + m16;
            float bkv = bkf[col], qv = qf[col];
            #pragma unroll
            for (int r=0;r<4;++r) {
                // fast tanh: (e^{2x}-1)/(e^{2x}+1), x clamped (tanh saturates)
                float xx = acc[nt][r] + bkv;
                xx = fminf(fmaxf(xx, -10.f), 10.f);
                float tex = __expf(2.f*xx);
                partial += qv * ((tex - 1.f) / (tex + 1.f));
            }
        }
    }
    __shared__ float red[256];
    red[t] = partial;
    __syncthreads();
    for (int s2 = 128; s2 > 0; s2 >>= 1) {
        if (t < s2) red[t] += red[t + s2];
        __syncthreads();
    }
    if (t == 0) unsafeAtomicAdd(&scores[mp], red[0]);
}

// ---------------- Beta ----------------
__global__ void k_beta(const float* __restrict__ scores, float* __restrict__ beta)
{
    float s0 = scores[0] / (float)NN;
    float s1 = scores[1] / (float)NN;
    float m = fmaxf(s0, s1);
    float e0 = __expf(s0-m), e1 = __expf(s1-m);
    float inv = 1.f/(e0+e1);
    beta[0] = e0*inv; beta[1] = e1*inv;
}

// ---------------- Final head (bf16 obf inputs) ----------------
__global__ __launch_bounds__(256) void k_final(
    const u16* __restrict__ obf0, const u16* __restrict__ obf1,
    const float* __restrict__ beta, const float* __restrict__ Wlf,
    const float* __restrict__ blf, const int* __restrict__ flag,
    void* __restrict__ outv)
{
    __shared__ float fus[16*128];
    __shared__ float WlL[384];
    __shared__ float blL[3];
    const int t = threadIdx.x;
    for (int i = t; i < 384; i += 256) WlL[i] = Wlf[i];
    if (t < 3) blL[t] = blf[t];
    float b0 = beta[0], b1 = beta[1];
    const u32* o0w = (const u32*)obf0;
    const u32* o1w = (const u32*)obf1;
    size_t base = (size_t)blockIdx.x * 16 * 64;   // u32 units
    #pragma unroll
    for (int i=0;i<4;++i) {
        int j = t + i*256;                         // 0..1023
        u32 v0 = o0w[base + j];
        u32 v1 = o1w[base + j];
        float l0 = fmaxf(b2f((u16)(v0&0xFFFF)),0.f), h0 = fmaxf(b2f((u16)(v0>>16)),0.f);
        float l1 = fmaxf(b2f((u16)(v1&0xFFFF)),0.f), h1 = fmaxf(b2f((u16)(v1>>16)),0.f);
        int row = j >> 6, cp = j & 63;
        fus[row*128 + cp*2]     = b0*l0 + b1*l1;
        fus[row*128 + cp*2 + 1] = b0*h0 + b1*h1;
    }
    __syncthreads();
    if (t < 48) {
        int node = t / 3, c = t % 3;
        float acc = blL[c];
        const float* fr = &fus[node*128];
        #pragma unroll 16
        for (int k=0;k<128;++k) acc += fr[k]*WlL[k*3+c];
        size_t oi = (size_t)(blockIdx.x*16 + node)*NOUT + c;
        if (flag[0]) ((float*)outv)[oi] = acc;
        else         ((__hip_bfloat16*)outv)[oi] = __float2bfloat16(acc);
    }
}

extern "C" void kernel_launch(void* const* d_in, const int* in_sizes, int n_in,
                              void* d_out, int out_size, void* d_ws, size_t ws_size,
                              hipStream_t stream)
{
    const void* x   = d_in[0];
    const int* ei0  = (const int*)d_in[1];
    const int* ei1  = (const int*)d_in[2];

    float* ws = (float*)d_ws;
    u16*   xpb     = (u16*)ws;                  // 6.4M u16 = 3,200,000 f
    float* a_src0  = ws +  3200000;
    float* a_dst0  = ws +  3600000;
    float* a_src1  = ws +  4000000;
    float* a_dst1  = ws +  4400000;
    u16*   obf0    = (u16*)(ws + 4800000);      // 3,200,000 f
    u16*   obf1    = (u16*)(ws + 8000000);      // 3,200,000 f
    int*   srt0    = (int*)(ws + 11200000);     // 1,000,000
    int*   srt1    = (int*)(ws + 12200000);     // 1,000,000
    int2*  tmp0    = (int2*)(ws + 13200000);    // 4,000,000 f
    int2*  tmp1    = (int2*)(ws + 17200000);    // 4,000,000 f
    int*   base0   = (int*)(ws + 21200000);     // 50,004
    int*   base1   = (int*)(ws + 21250004);     // 50,004
    float* scores  = ws + 21300008;             // 2
    int*   bcnt    = (int*)(ws + 21300010);     // 512
    int*   bstart  = (int*)(ws + 21300522);     // 400 (2 x 197, stride 200)
    float* beta    = ws + 21400010;             // 2
    int*   flag    = (int*)(ws + 21400012);     // 4 pad
    float* wconv   = ws + 21400016;             // 83,203
    int*   curA    = (int*)(ws + 21483348);     // 8,192 ints (64B-padded)
    u16*   WhiT    = (u16*)(ws + 21491540);     // 65,536 u16
    u16*   WloT    = (u16*)(ws + 21524308);     // 65,536 u16
    u16*   WkThi   = (u16*)(ws + 21557076);     // 16,384 u16
    // end ≈ 21,565,268 floats ≈ 86.3 MB

    // zero scores (2) + bcnt (512) in one shot (contiguous)
    hipMemsetAsync(scores, 0, (size_t)514 * sizeof(int), stream);

    k_detect<<<1, 256, 0, stream>>>(x, flag);
    k_convert<<<(W_TOT+255)/256, 256, 0, stream>>>(
        d_in[3], d_in[4], d_in[5], d_in[6], d_in[7], d_in[8],
        d_in[9], d_in[10], d_in[11], d_in[12], d_in[13], flag, wconv);
    k_prepw<<<(PREPN+255)/256, 256, 0, stream>>>(wconv + W_WP, wconv + W_WK,
                                                 WhiT, WloT, WkThi);

    // fp32 tiled fast path + bf16 tiled path; each early-exits on the wrong dtype
    k_projm_f32<<<(NN+127)/128, 256, 0, stream>>>(x, WhiT, WloT, wconv + W_BP, flag, xpb);
    k_projm_bf16<<<(NN+127)/128, 256, 0, stream>>>(x, WhiT, WloT, wconv + W_BP, flag, xpb);

    k_attcoef<<<(NN*NH + 255)/256, 256, 0, stream>>>(xpb, wconv + W_AS0,
                                                     a_src0, a_dst0, a_src1, a_dst1);
    k_bhist<<<dim3(NBLKA,2), 256, 0, stream>>>(ei0, ei1, bcnt);
    k_bscan<<<1, 512, 0, stream>>>(bcnt, bstart, curA);
    k_scatterA<<<dim3(NBLKA,2), 256, 0, stream>>>(ei0, ei1, curA, tmp0, tmp1);
    k_scatterB<<<dim3(NBUCK,2), 256, 0, stream>>>(tmp0, tmp1, bstart,
                                                  base0, base1, srt0, srt1);
    k_gather<<<dim3((NN + 3)/4, 2), 256, 0, stream>>>(
        srt0, srt1, base0, base1, a_src0, a_dst0, a_src1, a_dst1, xpb, obf0, obf1);

    k_semantic<<<dim3((NN/16 + 3)/4, 2), 256, 0, stream>>>(
        obf0, obf1, WkThi, wconv + W_BK, wconv + W_Q, scores);
    k_beta<<<1, 1, 0, stream>>>(scores, beta);
    k_final<<<NN/16, 256, 0, stream>>>(obf0, obf1, beta, wconv + W_WL, wconv + W_BL,
                                       flag, d_out);
}

// Round 6
// 405.954 us; speedup vs baseline: 1.0553x; 1.0553x over previous
//
#include <hip/hip_runtime.h>
#include <hip/hip_bf16.h>

#define NN 50000
#define EE 1000000
#define FIN 512
#define HIDDEN 128
#define NH 8
#define DH 16
#define NOUT 3
#define NBUCK 196   // ceil(NN/256) coarse dst buckets
#define EPB 8192    // edges per block in scatterA
#define NBLKA ((EE + EPB - 1) / EPB)   // 123
#define ATTBLK ((NN*NH + 255) / 256)   // 1563

typedef unsigned short u16;
typedef unsigned int u32;
typedef __attribute__((ext_vector_type(8))) short short8;
typedef __attribute__((ext_vector_type(4))) float f32x4;

__device__ __forceinline__ float b2f(u16 b) { return __uint_as_float(((u32)b) << 16); }
__device__ __forceinline__ u16 f2b(float f) { return (u16)(__float_as_uint(f) >> 16); }
__device__ __forceinline__ u16 f2b_rne(float f) {
    u32 u = __float_as_uint(f);
    return (u16)((u + 0x7FFFu + ((u >> 16) & 1u)) >> 16);
}

__device__ __forceinline__ void gload16(const u16* g, u16* l) {
    __builtin_amdgcn_global_load_lds(
        (const __attribute__((address_space(1))) unsigned int*)(g),
        (__attribute__((address_space(3))) unsigned int*)(l), 16, 0, 0);
}

// Converted-weight layout (fp32), offsets within wconv (Wp/Wk regions unused now):
#define W_BP   65536
#define W_AS0  65664
#define W_BK   82560
#define W_Q    82688
#define W_WL   82816
#define W_BL   83200

// ================= k_prep: per-block dtype detect + weight convert + W^T prep
// + workspace zeroing, all in ONE launch.
// blocks 0..255   : Wp -> WhiT/WloT (hi/lo bf16 split, transposed)
// blocks 256..319 : Wk -> WkThi (bf16 rne, transposed)
// block  320      : small weights -> wconv fp32
// blocks 321..352 : zero curA (8192 ints)
// block 0 thread 0 additionally publishes flag + zeroes scores.
__global__ __launch_bounds__(256) void k_prep(
    const void* __restrict__ x, const void* __restrict__ Wp, const void* __restrict__ Wk,
    const void* bp, const void* as0, const void* ad0, const void* as1, const void* ad1,
    const void* bk, const void* q, const void* Wl, const void* bl,
    int* __restrict__ flag, float* __restrict__ scores, int* __restrict__ curA,
    float* __restrict__ wconv, u16* __restrict__ WhiT, u16* __restrict__ WloT,
    u16* __restrict__ WkThi)
{
    const int t = threadIdx.x;
    const int bid = blockIdx.x;

    // local dtype detection: 256 samples; fp32 inputs -> low-half u16s are mantissa
    // garbage (insane ~0.7*256 = 179); bf16 inputs -> insane ~0. Threshold 64.
    const u16* xb = (const u16*)x;
    {
        float v = b2f(xb[((t*16 + (bid & 15))*131)*2]);
        float a = fabsf(v);
        int insane = ((a == 0.0f) || (a >= 1e-8f && a <= 1e4f)) ? 0 : 1;
        __shared__ int red[256];
        red[t] = insane;
        __syncthreads();
        for (int s = 128; s > 0; s >>= 1) { if (t < s) red[t] += red[t+s]; __syncthreads(); }
        const int f = (red[0] > 64) ? 1 : 0;
        if (bid == 0 && t == 0) { flag[0] = f; scores[0] = 0.f; scores[1] = 0.f; }

        if (bid < 256) {
            int idx = bid*256 + t;               // Wp row-major [k][n]
            float w = f ? ((const float*)Wp)[idx] : b2f(((const u16*)Wp)[idx]);
            int k = idx >> 7, n = idx & 127;
            u32 hb = __float_as_uint(w) & 0xFFFF0000u;
            WhiT[(size_t)n*FIN + k] = (u16)(hb >> 16);
            WloT[(size_t)n*FIN + k] = f2b(w - __uint_as_float(hb));
        } else if (bid < 320) {
            int i = (bid-256)*256 + t;           // Wk row-major [k][h]
            float w = f ? ((const float*)Wk)[i] : b2f(((const u16*)Wk)[i]);
            int k = i >> 7, h = i & 127;
            WkThi[(size_t)h*HIDDEN + k] = f2b_rne(w);
        } else if (bid == 320) {
            #pragma unroll
            for (int j = 0; j < 6; ++j) {
                int i = j*256 + t;
                if (i < 1283) {
                    const void* src; int off; int dst;
                    if (i < 640) {                   // bp,as0,ad0,as1,ad1 (contiguous at W_BP)
                        dst = W_BP + i;
                        if (i < 128)      { src = bp;  off = i; }
                        else if (i < 256) { src = as0; off = i-128; }
                        else if (i < 384) { src = ad0; off = i-256; }
                        else if (i < 512) { src = as1; off = i-384; }
                        else              { src = ad1; off = i-512; }
                    } else if (i < 896) {            // bk,q (contiguous at W_BK)
                        dst = W_BK + (i-640);
                        if (i < 768) { src = bk; off = i-640; }
                        else         { src = q;  off = i-768; }
                    } else {                         // Wl,bl (contiguous at W_WL)
                        dst = W_WL + (i-896);
                        if (i < 1280) { src = Wl; off = i-896; }
                        else          { src = bl; off = i-1280; }
                    }
                    wconv[dst] = f ? ((const float*)src)[off] : b2f(((const u16*)src)[off]);
                }
            }
        } else {
            int i = (bid-321)*256 + t;           // zero curA (bucket counters)
            if (i < 8192) curA[i] = 0;
        }
    }
}

// ================= Projection (fused dtype paths): 128x128 tile LDS MFMA GEMM ======
__global__ __launch_bounds__(256) void k_projm(
    const void* __restrict__ xv, const u16* __restrict__ WhiT,
    const u16* __restrict__ WloT, const float* __restrict__ bpf,
    const int* __restrict__ flag, u16* __restrict__ xpb)
{
    __shared__ u16 lds[2][16384];             // 64 KB (f32 path uses all; bf16 less)
    const int t = threadIdx.x;
    const int lane = t & 63;
    const int wid = t >> 6;
    const int m16 = lane & 15;
    const int quad = lane >> 4;
    const int wr = wid >> 1, wc = wid & 1;
    const int blockRow = blockIdx.x * 128;

    f32x4 acc[4][4];
    #pragma unroll
    for (int i = 0; i < 4; ++i)
        #pragma unroll
        for (int j = 0; j < 4; ++j) acc[i][j] = (f32x4)(0.f);

    if (flag[0]) {
        // ---------- fp32-input path ----------
        const float* xf = (const float*)xv;
        const int srow = t >> 1;
        const int shalf = t & 1;
        int gxrow = blockRow + srow; if (gxrow >= NN) gxrow = NN - 1;
        const float* xr = xf + (size_t)gxrow * FIN + shalf * 16;
        const int ssw = (srow >> 1) & 3;
        const int aw0 = srow*32 + ((shalf*2)     ^ ssw) * 8;
        const int aw1 = srow*32 + ((shalf*2 + 1) ^ ssw) * 8;

        int bp0 = t, bp1 = t + 256;
        int br0 = bp0 >> 2, br1 = bp1 >> 2;
        int bc0 = (bp0 & 3) ^ ((br0 >> 1) & 3);
        int bc1 = (bp1 & 3) ^ ((br1 >> 1) & 3);
        const u16* srcBh0 = WhiT + (size_t)br0 * FIN + bc0 * 8;
        const u16* srcBh1 = WhiT + (size_t)br1 * FIN + bc1 * 8;
        const u16* srcBl0 = WloT + (size_t)br0 * FIN + bc0 * 8;
        const u16* srcBl1 = WloT + (size_t)br1 * FIN + bc1 * 8;
        const int dB0 = bp0 * 8, dB1 = bp1 * 8;

        int aoff[4], boff[4];
        #pragma unroll
        for (int mt = 0; mt < 4; ++mt) {
            int r = wr*64 + mt*16 + m16;
            aoff[mt] = r*32 + ((quad ^ ((r >> 1) & 3)) << 3);
        }
        #pragma unroll
        for (int nt = 0; nt < 4; ++nt) {
            int r = wc*64 + nt*16 + m16;
            boff[nt] = r*32 + ((quad ^ ((r >> 1) & 3)) << 3);
        }

        u16* Lc = lds[0];
        u16* Ln = lds[1];
        {
            float4 v0 = *(const float4*)(xr);
            float4 v1 = *(const float4*)(xr + 4);
            float4 v2 = *(const float4*)(xr + 8);
            float4 v3 = *(const float4*)(xr + 12);
            gload16(srcBh0, Lc + 8192  + dB0);
            gload16(srcBh1, Lc + 8192  + dB1);
            gload16(srcBl0, Lc + 12288 + dB0);
            gload16(srcBl1, Lc + 12288 + dB1);
            float xs[16] = {v0.x,v0.y,v0.z,v0.w, v1.x,v1.y,v1.z,v1.w,
                            v2.x,v2.y,v2.z,v2.w, v3.x,v3.y,v3.z,v3.w};
            short8 h0, h1, l0, l1;
            #pragma unroll
            for (int j = 0; j < 8; ++j) {
                u32 u = __float_as_uint(xs[j]);   u32 hb = u & 0xFFFF0000u;
                h0[j] = (short)(hb >> 16); l0[j] = (short)f2b(xs[j] - __uint_as_float(hb));
                u32 u2 = __float_as_uint(xs[8+j]); u32 hb2 = u2 & 0xFFFF0000u;
                h1[j] = (short)(hb2 >> 16); l1[j] = (short)f2b(xs[8+j] - __uint_as_float(hb2));
            }
            *(short8*)(Lc + aw0) = h0;
            *(short8*)(Lc + aw1) = h1;
            *(short8*)(Lc + 4096 + aw0) = l0;
            *(short8*)(Lc + 4096 + aw1) = l1;
        }
        __syncthreads();

        #pragma unroll 1
        for (int ks = 0; ks < 16; ++ks) {
            const int kt = (ks + 1) * 32;
            float4 v0, v1, v2, v3;
            if (ks < 15) {
                v0 = *(const float4*)(xr + kt);
                v1 = *(const float4*)(xr + kt + 4);
                v2 = *(const float4*)(xr + kt + 8);
                v3 = *(const float4*)(xr + kt + 12);
                gload16(srcBh0 + kt, Ln + 8192  + dB0);
                gload16(srcBh1 + kt, Ln + 8192  + dB1);
                gload16(srcBl0 + kt, Ln + 12288 + dB0);
                gload16(srcBl1 + kt, Ln + 12288 + dB1);
            }
            short8 bh[4], bl[4];
            #pragma unroll
            for (int nt = 0; nt < 4; ++nt) {
                bh[nt] = *(const short8*)(Lc + 8192  + boff[nt]);
                bl[nt] = *(const short8*)(Lc + 12288 + boff[nt]);
            }
            #pragma unroll
            for (int mt = 0; mt < 4; ++mt) {
                short8 ah = *(const short8*)(Lc + aoff[mt]);
                short8 al = *(const short8*)(Lc + 4096 + aoff[mt]);
                #pragma unroll
                for (int nt = 0; nt < 4; ++nt) {
                    acc[mt][nt] = __builtin_amdgcn_mfma_f32_16x16x32_bf16(ah, bh[nt], acc[mt][nt], 0,0,0);
                    acc[mt][nt] = __builtin_amdgcn_mfma_f32_16x16x32_bf16(ah, bl[nt], acc[mt][nt], 0,0,0);
                    acc[mt][nt] = __builtin_amdgcn_mfma_f32_16x16x32_bf16(al, bh[nt], acc[mt][nt], 0,0,0);
                }
            }
            if (ks < 15) {
                float xs[16] = {v0.x,v0.y,v0.z,v0.w, v1.x,v1.y,v1.z,v1.w,
                                v2.x,v2.y,v2.z,v2.w, v3.x,v3.y,v3.z,v3.w};
                short8 h0, h1, l0, l1;
                #pragma unroll
                for (int j = 0; j < 8; ++j) {
                    u32 u = __float_as_uint(xs[j]);   u32 hb = u & 0xFFFF0000u;
                    h0[j] = (short)(hb >> 16); l0[j] = (short)f2b(xs[j] - __uint_as_float(hb));
                    u32 u2 = __float_as_uint(xs[8+j]); u32 hb2 = u2 & 0xFFFF0000u;
                    h1[j] = (short)(hb2 >> 16); l1[j] = (short)f2b(xs[8+j] - __uint_as_float(hb2));
                }
                *(short8*)(Ln + aw0) = h0;
                *(short8*)(Ln + aw1) = h1;
                *(short8*)(Ln + 4096 + aw0) = l0;
                *(short8*)(Ln + 4096 + aw1) = l1;
            }
            __syncthreads();
            u16* tmp = Lc; Lc = Ln; Ln = tmp;
        }
    } else {
        // ---------- bf16-input path ----------
        const u16* xb = (const u16*)xv;
        const int r0 = t >> 2,         c0 = (t & 3) * 8;
        const int r1 = (t + 256) >> 2, c1 = ((t + 256) & 3) * 8;
        int g0 = blockRow + r0; if (g0 >= NN) g0 = NN - 1;
        int g1 = blockRow + r1; if (g1 >= NN) g1 = NN - 1;
        const u16* srcA0  = xb   + (size_t)g0 * FIN + c0;
        const u16* srcA1  = xb   + (size_t)g1 * FIN + c1;
        const u16* srcBh0 = WhiT + (size_t)r0 * FIN + c0;
        const u16* srcBh1 = WhiT + (size_t)r1 * FIN + c1;
        const u16* srcBl0 = WloT + (size_t)r0 * FIN + c0;
        const u16* srcBl1 = WloT + (size_t)r1 * FIN + c1;

#define PSTAGE(buf, kt) do { \
        gload16(srcA0  + (kt), &lds[buf][t*8]); \
        gload16(srcA1  + (kt), &lds[buf][2048 + t*8]); \
        gload16(srcBh0 + (kt), &lds[buf][4096 + t*8]); \
        gload16(srcBh1 + (kt), &lds[buf][6144 + t*8]); \
        gload16(srcBl0 + (kt), &lds[buf][8192 + t*8]); \
        gload16(srcBl1 + (kt), &lds[buf][10240 + t*8]); \
    } while (0)

        PSTAGE(0, 0);
        __syncthreads();
        int cur = 0;
        for (int ks = 0; ks < 16; ++ks) {
            if (ks < 15) {
                if (cur) PSTAGE(0, (ks + 1) * 32);
                else     PSTAGE(1, (ks + 1) * 32);
            }
            const u16* L = lds[cur];
            short8 a[4], bh[4], bl[4];
            #pragma unroll
            for (int mt = 0; mt < 4; ++mt)
                a[mt] = *(const short8*)&L[(wr*64 + mt*16 + m16)*32 + quad*8];
            #pragma unroll
            for (int nt = 0; nt < 4; ++nt) {
                bh[nt] = *(const short8*)&L[4096 + (wc*64 + nt*16 + m16)*32 + quad*8];
                bl[nt] = *(const short8*)&L[8192 + (wc*64 + nt*16 + m16)*32 + quad*8];
            }
            #pragma unroll
            for (int mt = 0; mt < 4; ++mt)
                #pragma unroll
                for (int nt = 0; nt < 4; ++nt) {
                    acc[mt][nt] = __builtin_amdgcn_mfma_f32_16x16x32_bf16(a[mt], bh[nt], acc[mt][nt], 0,0,0);
                    acc[mt][nt] = __builtin_amdgcn_mfma_f32_16x16x32_bf16(a[mt], bl[nt], acc[mt][nt], 0,0,0);
                }
            __syncthreads();
            cur ^= 1;
        }
#undef PSTAGE
    }

    // epilogue (shared): C/D layout col=lane&15, row=(lane>>4)*4+reg
    #pragma unroll
    for (int nt = 0; nt < 4; ++nt) {
        int col = wc*64 + nt*16 + m16;
        float bias = bpf[col];
        #pragma unroll
        for (int mt = 0; mt < 4; ++mt) {
            int orow0 = blockRow + wr*64 + mt*16 + quad*4;
            #pragma unroll
            for (int r = 0; r < 4; ++r) {
                int orow = orow0 + r;
                if (orow < NN) xpb[(size_t)orow*HIDDEN + col] = f2b_rne(acc[mt][nt][r] + bias);
            }
        }
    }
}

// ================= Fused: attcoef (blocks 0..1562)  ||  scatterA (blocks 1563..1808)
// Independent work, one launch. scatterA writes packed (dloc<<16)|src into fixed
// 8192-slot bucket segments (mean fill 5102, +43 sigma margin) -> no global scan.
__global__ __launch_bounds__(256) void k_fused1(
    const u16* __restrict__ xpb, const float* __restrict__ watt,
    float* __restrict__ o_as0, float* __restrict__ o_ad0,
    float* __restrict__ o_as1, float* __restrict__ o_ad1,
    const int* __restrict__ ei0, const int* __restrict__ ei1,
    int* __restrict__ curA, u32* __restrict__ tmp0, u32* __restrict__ tmp1)
{
    __shared__ int sh[768];
    const int t = threadIdx.x;
    const int bid = blockIdx.x;

    if (bid < ATTBLK) {
        // ---- attcoef ----
        float* s0 = (float*)sh;
        float* d0 = s0 + 128;
        float* s1 = s0 + 256;
        float* d1 = s0 + 384;
        if (t < 128) { s0[t]=watt[t]; d0[t]=watt[128+t]; s1[t]=watt[256+t]; d1[t]=watt[384+t]; }
        __syncthreads();
        int tid = bid*256 + t;               // n*8 + h
        if (tid >= NN*NH) return;
        int h = tid & 7;
        const u32* px = (const u32*)(xpb + (size_t)tid * DH);
        float xv[16];
        #pragma unroll
        for (int i=0;i<8;++i){ u32 v=px[i]; xv[i*2]=b2f((u16)(v&0xFFFF)); xv[i*2+1]=b2f((u16)(v>>16)); }
        float r0=0.f,r1=0.f,r2=0.f,r3=0.f;
        #pragma unroll
        for (int d=0; d<16; ++d) {
            float xvd = xv[d];
            r0 += xvd*s0[h*16+d]; r1 += xvd*d0[h*16+d];
            r2 += xvd*s1[h*16+d]; r3 += xvd*d1[h*16+d];
        }
        o_as0[tid]=r0; o_ad0[tid]=r1; o_as1[tid]=r2; o_ad1[tid]=r3;
    } else {
        // ---- scatterA ----
        int r = bid - ATTBLK;
        const int mp = (r >= NBLKA) ? 1 : 0;
        const int bx = r - mp*NBLKA;
        const int* ei = mp ? ei1 : ei0;
        u32* tmp = mp ? tmp1 : tmp0;
        int* hist = sh;
        int* seg  = sh + 256;
        int* cnt  = sh + 512;
        for (int b = t; b < NBUCK; b += 256) hist[b] = 0;
        __syncthreads();
        const int e0 = bx * EPB;
        #pragma unroll
        for (int i = 0; i < EPB/256; ++i) {
            int idx = e0 + i*256 + t;
            if (idx < EE) atomicAdd(&hist[ei[EE + idx] >> 8], 1);
        }
        __syncthreads();
        for (int b = t; b < NBUCK; b += 256) {
            int h = hist[b];
            seg[b] = h ? atomicAdd(&curA[(mp*256 + b)*16], h) : 0;
            cnt[b] = 0;
        }
        __syncthreads();
        #pragma unroll
        for (int i = 0; i < EPB/256; ++i) {
            int idx = e0 + i*256 + t;
            if (idx < EE) {
                int s = ei[idx], d = ei[EE + idx];
                int b = d >> 8;
                int pos = seg[b] + atomicAdd(&cnt[b], 1);
                tmp[((size_t)b << 13) + pos] = (u32)(((d & 255) << 16) | s);
            }
        }
    }
}

// ================= Scatter pass B: per-bucket count+scan -> nstart/ncnt and srt ======
__global__ __launch_bounds__(256) void k_scatterB(
    const u32* __restrict__ tmp0, const u32* __restrict__ tmp1,
    const int* __restrict__ bcap,
    int* __restrict__ ns0, int* __restrict__ ns1,
    int* __restrict__ nc0, int* __restrict__ nc1,
    int* __restrict__ srt0, int* __restrict__ srt1)
{
    const int b = blockIdx.x;
    const int mp = blockIdx.y;
    const u32* tmp = mp ? tmp1 : tmp0;
    int* nstart = mp ? ns1 : ns0;
    int* ncnt   = mp ? nc1 : nc0;
    int* srt    = mp ? srt1 : srt0;
    const int cntb = bcap[(mp*256 + b)*16];
    const int segbase = b << 13;
    __shared__ int lcnt[256];
    __shared__ int loff[256];
    const int t = threadIdx.x;
    lcnt[t] = 0;
    __syncthreads();
    for (int i = t; i < cntb; i += 256)
        atomicAdd(&lcnt[tmp[segbase + i] >> 16], 1);
    __syncthreads();
    int v = lcnt[t];
    loff[t] = v;
    __syncthreads();
    for (int off = 1; off < 256; off <<= 1) {
        int u = (t >= off) ? loff[t - off] : 0;
        __syncthreads();
        loff[t] += u;
        __syncthreads();
    }
    int excl = loff[t] - v;
    int node = (b << 8) + t;
    if (node < NN) { nstart[node] = segbase + excl; ncnt[node] = v; }
    __syncthreads();
    loff[t] = excl;
    lcnt[t] = 0;
    __syncthreads();
    for (int i = t; i < cntb; i += 256) {
        u32 p = tmp[segbase + i];
        int local = p >> 16;
        int pos = segbase + loff[local] + atomicAdd(&lcnt[local], 1);
        srt[pos] = (int)(p & 0xFFFFu);
    }
}

// ================= Gather (round-4 v2): 8 edges/iter; weights 8x8 (edge x head)
// in one shot, redistributed via ds_bpermute; row bases via readlane->SGPR. =======
__global__ __launch_bounds__(256) void k_gather(
    const int* __restrict__ srt0, const int* __restrict__ srt1,
    const int* __restrict__ ns0, const int* __restrict__ ns1,
    const int* __restrict__ nc0, const int* __restrict__ nc1,
    const float* __restrict__ as0, const float* __restrict__ ad0,
    const float* __restrict__ as1, const float* __restrict__ ad1,
    const u16* __restrict__ xpb, u16* __restrict__ obf0, u16* __restrict__ obf1)
{
    const int t = threadIdx.x;
    const int wid = blockIdx.x*4 + (t >> 6);
    if (wid >= NN) return;
    const int lane = t & 63;
    const int hc = lane & 7;        // head in weight-compute phase
    const int eg = lane >> 3;       // edge slot in chunk (weight phase)
    const int mp = blockIdx.y;
    const int*  srt  = mp ? srt1  : srt0;
    const int*  nstart = mp ? ns1 : ns0;
    const int*  ncnt   = mp ? nc1 : nc0;
    const float* asr = mp ? as1 : as0;
    const float* ads = mp ? ad1 : ad0;
    u16* obf = mp ? obf1 : obf0;
    const u32* xw = (const u32*)xpb;     // 64 u32 per row

    const int b = nstart[wid], e = b + ncnt[wid];
    const float adv = ads[wid*NH + hc];          // dst coefficient, head hc
    const int bp = (lane >> 3) << 2;             // bpermute base addr: h_out = lane>>3
    float accx = 0.f, accy = 0.f, den = 0.f;

    for (int i = b; i < e; i += 8) {
        int il = i + eg;
        int ilc = il < e ? il : e - 1;           // clamp for safe loads
        int s = srt[ilc];                        // 8 distinct edges, coalesced

        u32 rv0, rv1, rv2, rv3, rv4, rv5, rv6, rv7;
        {
            const u32* r0p = xw + ((size_t)(u32)__builtin_amdgcn_readlane(s, 0)  << 6);
            const u32* r1p = xw + ((size_t)(u32)__builtin_amdgcn_readlane(s, 8)  << 6);
            const u32* r2p = xw + ((size_t)(u32)__builtin_amdgcn_readlane(s, 16) << 6);
            const u32* r3p = xw + ((size_t)(u32)__builtin_amdgcn_readlane(s, 24) << 6);
            const u32* r4p = xw + ((size_t)(u32)__builtin_amdgcn_readlane(s, 32) << 6);
            const u32* r5p = xw + ((size_t)(u32)__builtin_amdgcn_readlane(s, 40) << 6);
            const u32* r6p = xw + ((size_t)(u32)__builtin_amdgcn_readlane(s, 48) << 6);
            const u32* r7p = xw + ((size_t)(u32)__builtin_amdgcn_readlane(s, 56) << 6);
            rv0 = r0p[lane]; rv1 = r1p[lane]; rv2 = r2p[lane]; rv3 = r3p[lane];
            rv4 = r4p[lane]; rv5 = r5p[lane]; rv6 = r6p[lane]; rv7 = r7p[lane];
        }

        float av = asr[s*NH + hc] + adv;
        av = fmaxf(av, 0.2f*av);                 // leaky_relu, slope<1
        float w = (il < e) ? __expf(av) : 0.f;   // mask invalid edges
        int wi = __float_as_int(w);

        #pragma unroll
        for (int k2 = 0; k2 < 8; ++k2) {
            float wk = __int_as_float(__builtin_amdgcn_ds_bpermute(bp + k2*32, wi));
            u32 v = (k2==0)?rv0:(k2==1)?rv1:(k2==2)?rv2:(k2==3)?rv3:
                    (k2==4)?rv4:(k2==5)?rv5:(k2==6)?rv6:rv7;
            accx = fmaf(wk, b2f((u16)(v & 0xFFFF)), accx);
            accy = fmaf(wk, b2f((u16)(v >> 16)), accy);
            den += wk;
        }
    }
    float inv = 1.f / (den + 1e-16f);
    u32 lo = f2b_rne(accx*inv), hi = f2b_rne(accy*inv);
    ((u32*)obf)[(size_t)wid*64 + lane] = (hi << 16) | lo;
}

// ================= Semantic scores via MFMA (bf16 obf direct A-operand) =============
__global__ __launch_bounds__(256) void k_semantic(
    const u16* __restrict__ obf0, const u16* __restrict__ obf1,
    const u16* __restrict__ WkThi, const float* __restrict__ bkf,
    const float* __restrict__ qf, float* __restrict__ scores)
{
    const int t = threadIdx.x;
    const int lane = t & 63;
    const int w = t >> 6;
    const int m16 = lane & 15;
    const int quad = lane >> 4;
    const int mp = blockIdx.y;
    const u16* om = mp ? obf1 : obf0;
    const int tile = blockIdx.x*4 + w;

    float partial = 0.f;
    if (tile < NN/16) {
        int row = tile*16 + m16;
        f32x4 acc[8];
        #pragma unroll
        for (int i=0;i<8;++i) acc[i] = (f32x4)(0.f);

        for (int kt = 0; kt < HIDDEN; kt += 32) {
            int kbase = kt + quad*8;
            short8 a = *(const short8*)(om + (size_t)row*HIDDEN + kbase);
            #pragma unroll
            for (int j=0;j<8;++j) a[j] = ((u16)a[j] & 0x8000u) ? (short)0 : a[j];  // relu in bf16
            #pragma unroll
            for (int nt = 0; nt < 8; ++nt) {
                int n = nt*16 + m16;
                short8 bhi = *(const short8*)(WkThi + (size_t)n*HIDDEN + kbase);
                acc[nt] = __builtin_amdgcn_mfma_f32_16x16x32_bf16(a, bhi, acc[nt], 0,0,0);
            }
        }
        #pragma unroll
        for (int nt=0; nt<8; ++nt) {
            int col = nt*16 + m16;
            float bkv = bkf[col], qv = qf[col];
            #pragma unroll
            for (int r=0;r<4;++r) {
                // fast tanh: (e^{2x}-1)/(e^{2x}+1), clamped (tanh saturates)
                float xx = acc[nt][r] + bkv;
                xx = fminf(fmaxf(xx, -10.f), 10.f);
                float tex = __expf(2.f*xx);
                partial += qv * ((tex - 1.f) / (tex + 1.f));
            }
        }
    }
    __shared__ float red[256];
    red[t] = partial;
    __syncthreads();
    for (int s2 = 128; s2 > 0; s2 >>= 1) {
        if (t < s2) red[t] += red[t + s2];
        __syncthreads();
    }
    if (t == 0) unsafeAtomicAdd(&scores[mp], red[0]);
}

// ================= Final head (beta computed inline from scores) ====================
__global__ __launch_bounds__(256) void k_final(
    const u16* __restrict__ obf0, const u16* __restrict__ obf1,
    const float* __restrict__ scores, const float* __restrict__ Wlf,
    const float* __restrict__ blf, const int* __restrict__ flag,
    void* __restrict__ outv)
{
    __shared__ float fus[16*128];
    __shared__ float WlL[384];
    __shared__ float blL[3];
    const int t = threadIdx.x;
    for (int i = t; i < 384; i += 256) WlL[i] = Wlf[i];
    if (t < 3) blL[t] = blf[t];
    // beta inline (identical numerics to old k_beta)
    float sc0 = scores[0] / (float)NN;
    float sc1 = scores[1] / (float)NN;
    float m = fmaxf(sc0, sc1);
    float e0 = __expf(sc0-m), e1 = __expf(sc1-m);
    float binv = 1.f/(e0+e1);
    float b0 = e0*binv, b1 = e1*binv;

    const u32* o0w = (const u32*)obf0;
    const u32* o1w = (const u32*)obf1;
    size_t base = (size_t)blockIdx.x * 16 * 64;   // u32 units
    #pragma unroll
    for (int i=0;i<4;++i) {
        int j = t + i*256;                         // 0..1023
        u32 v0 = o0w[base + j];
        u32 v1 = o1w[base + j];
        float l0 = fmaxf(b2f((u16)(v0&0xFFFF)),0.f), h0 = fmaxf(b2f((u16)(v0>>16)),0.f);
        float l1 = fmaxf(b2f((u16)(v1&0xFFFF)),0.f), h1 = fmaxf(b2f((u16)(v1>>16)),0.f);
        int row = j >> 6, cp = j & 63;
        fus[row*128 + cp*2]     = b0*l0 + b1*l1;
        fus[row*128 + cp*2 + 1] = b0*h0 + b1*h1;
    }
    __syncthreads();
    if (t < 48) {
        int node = t / 3, c = t % 3;
        float acc = blL[c];
        const float* fr = &fus[node*128];
        #pragma unroll 16
        for (int k=0;k<128;++k) acc += fr[k]*WlL[k*3+c];
        size_t oi = (size_t)(blockIdx.x*16 + node)*NOUT + c;
        if (flag[0]) ((float*)outv)[oi] = acc;
        else         ((__hip_bfloat16*)outv)[oi] = __float2bfloat16(acc);
    }
}

extern "C" void kernel_launch(void* const* d_in, const int* in_sizes, int n_in,
                              void* d_out, int out_size, void* d_ws, size_t ws_size,
                              hipStream_t stream)
{
    const void* x   = d_in[0];
    const int* ei0  = (const int*)d_in[1];
    const int* ei1  = (const int*)d_in[2];

    float* ws = (float*)d_ws;
    u16*   xpb     = (u16*)ws;                  // 3,200,000 f
    float* a_src0  = ws +  3200000;             // 400,000 each
    float* a_dst0  = ws +  3600000;
    float* a_src1  = ws +  4000000;
    float* a_dst1  = ws +  4400000;
    u16*   obf0    = (u16*)(ws + 4800000);      // 3,200,000 f
    u16*   obf1    = (u16*)(ws + 8000000);      // 3,200,000 f
    int*   srt0    = (int*)(ws + 11200000);     // 1,605,632 (padded bucket segments)
    int*   srt1    = (int*)(ws + 12810000);
    u32*   tmp0    = (u32*)(ws + 14420000);     // 1,605,632 packed u32
    u32*   tmp1    = (u32*)(ws + 16030000);
    int*   nstart0 = (int*)(ws + 17640000);     // 50,000 each
    int*   nstart1 = (int*)(ws + 17690000);
    int*   ncnt0   = (int*)(ws + 17740000);
    int*   ncnt1   = (int*)(ws + 17790000);
    float* scores  = ws + 17840000;             // 2
    int*   flag    = (int*)(ws + 17840004);
    float* wconv   = ws + 17840008;             // 83,203 (only small-weight regions used)
    int*   curA    = (int*)(ws + 17923216);     // 8,192 ints (bucket counters, 64B-padded)
    u16*   WhiT    = (u16*)(ws + 17931408);     // 65,536 u16
    u16*   WloT    = (u16*)(ws + 17964176);     // 65,536 u16
    u16*   WkThi   = (u16*)(ws + 17996944);     // 16,384 u16
    // end ~ 18,005,136 floats ~ 72 MB

    // 7 launches total (was 16): launch overhead + two full passes eliminated.
    k_prep<<<353, 256, 0, stream>>>(
        x, d_in[3], d_in[9], d_in[4], d_in[5], d_in[6], d_in[7], d_in[8],
        d_in[10], d_in[11], d_in[12], d_in[13],
        flag, scores, curA, wconv, WhiT, WloT, WkThi);

    k_projm<<<(NN+127)/128, 256, 0, stream>>>(x, WhiT, WloT, wconv + W_BP, flag, xpb);

    k_fused1<<<ATTBLK + 2*NBLKA, 256, 0, stream>>>(
        xpb, wconv + W_AS0, a_src0, a_dst0, a_src1, a_dst1,
        ei0, ei1, curA, tmp0, tmp1);

    k_scatterB<<<dim3(NBUCK,2), 256, 0, stream>>>(
        tmp0, tmp1, curA, nstart0, nstart1, ncnt0, ncnt1, srt0, srt1);

    k_gather<<<dim3((NN + 3)/4, 2), 256, 0, stream>>>(
        srt0, srt1, nstart0, nstart1, ncnt0, ncnt1,
        a_src0, a_dst0, a_src1, a_dst1, xpb, obf0, obf1);

    k_semantic<<<dim3((NN/16 + 3)/4, 2), 256, 0, stream>>>(
        obf0, obf1, WkThi, wconv + W_BK, wconv + W_Q, scores);

    k_final<<<NN/16, 256, 0, stream>>>(obf0, obf1, scores, wconv + W_WL, wconv + W_BL,
                                       flag, d_out);
}

// Round 7
// 396.187 us; speedup vs baseline: 1.0813x; 1.0247x over previous
//
#include <hip/hip_runtime.h>
#include <hip/hip_bf16.h>

#define NN 50000
#define EE 1000000
#define FIN 512
#define HIDDEN 128
#define NH 8
#define DH 16
#define NOUT 3
#define NBUCK 196   // ceil(NN/256) coarse dst buckets
#define EPB 8192    // edges per block in scatterA
#define NBLKA ((EE + EPB - 1) / EPB)   // 123
#define ATTBLK ((NN*NH + 255) / 256)   // 1563

typedef unsigned short u16;
typedef unsigned int u32;
typedef __attribute__((ext_vector_type(8))) short short8;
typedef __attribute__((ext_vector_type(4))) float f32x4;

__device__ __forceinline__ float b2f(u16 b) { return __uint_as_float(((u32)b) << 16); }
__device__ __forceinline__ u16 f2b(float f) { return (u16)(__float_as_uint(f) >> 16); }
__device__ __forceinline__ u16 f2b_rne(float f) {
    u32 u = __float_as_uint(f);
    return (u16)((u + 0x7FFFu + ((u >> 16) & 1u)) >> 16);
}

__device__ __forceinline__ void gload16(const u16* g, u16* l) {
    __builtin_amdgcn_global_load_lds(
        (const __attribute__((address_space(1))) unsigned int*)(g),
        (__attribute__((address_space(3))) unsigned int*)(l), 16, 0, 0);
}

// Converted-weight layout (fp32), offsets within wconv (Wp/Wk regions unused now):
#define W_BP   65536
#define W_AS0  65664
#define W_BK   82560
#define W_Q    82688
#define W_WL   82816
#define W_BL   83200

// ================= k_prep: per-block dtype detect + weight convert + W^T prep
// + workspace zeroing, all in ONE launch.
__global__ __launch_bounds__(256) void k_prep(
    const void* __restrict__ x, const void* __restrict__ Wp, const void* __restrict__ Wk,
    const void* bp, const void* as0, const void* ad0, const void* as1, const void* ad1,
    const void* bk, const void* q, const void* Wl, const void* bl,
    int* __restrict__ flag, float* __restrict__ scores, int* __restrict__ curA,
    float* __restrict__ wconv, u16* __restrict__ WhiT, u16* __restrict__ WloT,
    u16* __restrict__ WkThi)
{
    const int t = threadIdx.x;
    const int bid = blockIdx.x;

    const u16* xb = (const u16*)x;
    {
        float v = b2f(xb[((t*16 + (bid & 15))*131)*2]);
        float a = fabsf(v);
        int insane = ((a == 0.0f) || (a >= 1e-8f && a <= 1e4f)) ? 0 : 1;
        __shared__ int red[256];
        red[t] = insane;
        __syncthreads();
        for (int s = 128; s > 0; s >>= 1) { if (t < s) red[t] += red[t+s]; __syncthreads(); }
        const int f = (red[0] > 64) ? 1 : 0;
        if (bid == 0 && t == 0) { flag[0] = f; scores[0] = 0.f; scores[1] = 0.f; }

        if (bid < 256) {
            int idx = bid*256 + t;               // Wp row-major [k][n]
            float w = f ? ((const float*)Wp)[idx] : b2f(((const u16*)Wp)[idx]);
            int k = idx >> 7, n = idx & 127;
            u32 hb = __float_as_uint(w) & 0xFFFF0000u;
            WhiT[(size_t)n*FIN + k] = (u16)(hb >> 16);
            WloT[(size_t)n*FIN + k] = f2b(w - __uint_as_float(hb));
        } else if (bid < 320) {
            int i = (bid-256)*256 + t;           // Wk row-major [k][h]
            float w = f ? ((const float*)Wk)[i] : b2f(((const u16*)Wk)[i]);
            int k = i >> 7, h = i & 127;
            WkThi[(size_t)h*HIDDEN + k] = f2b_rne(w);
        } else if (bid == 320) {
            #pragma unroll
            for (int j = 0; j < 6; ++j) {
                int i = j*256 + t;
                if (i < 1283) {
                    const void* src; int off; int dst;
                    if (i < 640) {
                        dst = W_BP + i;
                        if (i < 128)      { src = bp;  off = i; }
                        else if (i < 256) { src = as0; off = i-128; }
                        else if (i < 384) { src = ad0; off = i-256; }
                        else if (i < 512) { src = as1; off = i-384; }
                        else              { src = ad1; off = i-512; }
                    } else if (i < 896) {
                        dst = W_BK + (i-640);
                        if (i < 768) { src = bk; off = i-640; }
                        else         { src = q;  off = i-768; }
                    } else {
                        dst = W_WL + (i-896);
                        if (i < 1280) { src = Wl; off = i-896; }
                        else          { src = bl; off = i-1280; }
                    }
                    wconv[dst] = f ? ((const float*)src)[off] : b2f(((const u16*)src)[off]);
                }
            }
        } else {
            int i = (bid-321)*256 + t;           // zero curA (bucket counters)
            if (i < 8192) curA[i] = 0;
        }
    }
}

// ================= Projection (fused dtype paths): 128x128 tile LDS MFMA GEMM ======
__global__ __launch_bounds__(256) void k_projm(
    const void* __restrict__ xv, const u16* __restrict__ WhiT,
    const u16* __restrict__ WloT, const float* __restrict__ bpf,
    const int* __restrict__ flag, u16* __restrict__ xpb)
{
    __shared__ u16 lds[2][16384];             // 64 KB
    const int t = threadIdx.x;
    const int lane = t & 63;
    const int wid = t >> 6;
    const int m16 = lane & 15;
    const int quad = lane >> 4;
    const int wr = wid >> 1, wc = wid & 1;
    const int blockRow = blockIdx.x * 128;

    f32x4 acc[4][4];
    #pragma unroll
    for (int i = 0; i < 4; ++i)
        #pragma unroll
        for (int j = 0; j < 4; ++j) acc[i][j] = (f32x4)(0.f);

    if (flag[0]) {
        // ---------- fp32-input path ----------
        const float* xf = (const float*)xv;
        const int srow = t >> 1;
        const int shalf = t & 1;
        int gxrow = blockRow + srow; if (gxrow >= NN) gxrow = NN - 1;
        const float* xr = xf + (size_t)gxrow * FIN + shalf * 16;
        const int ssw = (srow >> 1) & 3;
        const int aw0 = srow*32 + ((shalf*2)     ^ ssw) * 8;
        const int aw1 = srow*32 + ((shalf*2 + 1) ^ ssw) * 8;

        int bp0 = t, bp1 = t + 256;
        int br0 = bp0 >> 2, br1 = bp1 >> 2;
        int bc0 = (bp0 & 3) ^ ((br0 >> 1) & 3);
        int bc1 = (bp1 & 3) ^ ((br1 >> 1) & 3);
        const u16* srcBh0 = WhiT + (size_t)br0 * FIN + bc0 * 8;
        const u16* srcBh1 = WhiT + (size_t)br1 * FIN + bc1 * 8;
        const u16* srcBl0 = WloT + (size_t)br0 * FIN + bc0 * 8;
        const u16* srcBl1 = WloT + (size_t)br1 * FIN + bc1 * 8;
        const int dB0 = bp0 * 8, dB1 = bp1 * 8;

        int aoff[4], boff[4];
        #pragma unroll
        for (int mt = 0; mt < 4; ++mt) {
            int r = wr*64 + mt*16 + m16;
            aoff[mt] = r*32 + ((quad ^ ((r >> 1) & 3)) << 3);
        }
        #pragma unroll
        for (int nt = 0; nt < 4; ++nt) {
            int r = wc*64 + nt*16 + m16;
            boff[nt] = r*32 + ((quad ^ ((r >> 1) & 3)) << 3);
        }

        u16* Lc = lds[0];
        u16* Ln = lds[1];
        {
            float4 v0 = *(const float4*)(xr);
            float4 v1 = *(const float4*)(xr + 4);
            float4 v2 = *(const float4*)(xr + 8);
            float4 v3 = *(const float4*)(xr + 12);
            gload16(srcBh0, Lc + 8192  + dB0);
            gload16(srcBh1, Lc + 8192  + dB1);
            gload16(srcBl0, Lc + 12288 + dB0);
            gload16(srcBl1, Lc + 12288 + dB1);
            float xs[16] = {v0.x,v0.y,v0.z,v0.w, v1.x,v1.y,v1.z,v1.w,
                            v2.x,v2.y,v2.z,v2.w, v3.x,v3.y,v3.z,v3.w};
            short8 h0, h1, l0, l1;
            #pragma unroll
            for (int j = 0; j < 8; ++j) {
                u32 u = __float_as_uint(xs[j]);   u32 hb = u & 0xFFFF0000u;
                h0[j] = (short)(hb >> 16); l0[j] = (short)f2b(xs[j] - __uint_as_float(hb));
                u32 u2 = __float_as_uint(xs[8+j]); u32 hb2 = u2 & 0xFFFF0000u;
                h1[j] = (short)(hb2 >> 16); l1[j] = (short)f2b(xs[8+j] - __uint_as_float(hb2));
            }
            *(short8*)(Lc + aw0) = h0;
            *(short8*)(Lc + aw1) = h1;
            *(short8*)(Lc + 4096 + aw0) = l0;
            *(short8*)(Lc + 4096 + aw1) = l1;
        }
        __syncthreads();

        #pragma unroll 1
        for (int ks = 0; ks < 16; ++ks) {
            const int kt = (ks + 1) * 32;
            float4 v0, v1, v2, v3;
            if (ks < 15) {
                v0 = *(const float4*)(xr + kt);
                v1 = *(const float4*)(xr + kt + 4);
                v2 = *(const float4*)(xr + kt + 8);
                v3 = *(const float4*)(xr + kt + 12);
                gload16(srcBh0 + kt, Ln + 8192  + dB0);
                gload16(srcBh1 + kt, Ln + 8192  + dB1);
                gload16(srcBl0 + kt, Ln + 12288 + dB0);
                gload16(srcBl1 + kt, Ln + 12288 + dB1);
            }
            short8 bh[4], bl[4];
            #pragma unroll
            for (int nt = 0; nt < 4; ++nt) {
                bh[nt] = *(const short8*)(Lc + 8192  + boff[nt]);
                bl[nt] = *(const short8*)(Lc + 12288 + boff[nt]);
            }
            #pragma unroll
            for (int mt = 0; mt < 4; ++mt) {
                short8 ah = *(const short8*)(Lc + aoff[mt]);
                short8 al = *(const short8*)(Lc + 4096 + aoff[mt]);
                #pragma unroll
                for (int nt = 0; nt < 4; ++nt) {
                    acc[mt][nt] = __builtin_amdgcn_mfma_f32_16x16x32_bf16(ah, bh[nt], acc[mt][nt], 0,0,0);
                    acc[mt][nt] = __builtin_amdgcn_mfma_f32_16x16x32_bf16(ah, bl[nt], acc[mt][nt], 0,0,0);
                    acc[mt][nt] = __builtin_amdgcn_mfma_f32_16x16x32_bf16(al, bh[nt], acc[mt][nt], 0,0,0);
                }
            }
            if (ks < 15) {
                float xs[16] = {v0.x,v0.y,v0.z,v0.w, v1.x,v1.y,v1.z,v1.w,
                                v2.x,v2.y,v2.z,v2.w, v3.x,v3.y,v3.z,v3.w};
                short8 h0, h1, l0, l1;
                #pragma unroll
                for (int j = 0; j < 8; ++j) {
                    u32 u = __float_as_uint(xs[j]);   u32 hb = u & 0xFFFF0000u;
                    h0[j] = (short)(hb >> 16); l0[j] = (short)f2b(xs[j] - __uint_as_float(hb));
                    u32 u2 = __float_as_uint(xs[8+j]); u32 hb2 = u2 & 0xFFFF0000u;
                    h1[j] = (short)(hb2 >> 16); l1[j] = (short)f2b(xs[8+j] - __uint_as_float(hb2));
                }
                *(short8*)(Ln + aw0) = h0;
                *(short8*)(Ln + aw1) = h1;
                *(short8*)(Ln + 4096 + aw0) = l0;
                *(short8*)(Ln + 4096 + aw1) = l1;
            }
            __syncthreads();
            u16* tmp = Lc; Lc = Ln; Ln = tmp;
        }
    } else {
        // ---------- bf16-input path ----------
        const u16* xb = (const u16*)xv;
        const int r0 = t >> 2,         c0 = (t & 3) * 8;
        const int r1 = (t + 256) >> 2, c1 = ((t + 256) & 3) * 8;
        int g0 = blockRow + r0; if (g0 >= NN) g0 = NN - 1;
        int g1 = blockRow + r1; if (g1 >= NN) g1 = NN - 1;
        const u16* srcA0  = xb   + (size_t)g0 * FIN + c0;
        const u16* srcA1  = xb   + (size_t)g1 * FIN + c1;
        const u16* srcBh0 = WhiT + (size_t)r0 * FIN + c0;
        const u16* srcBh1 = WhiT + (size_t)r1 * FIN + c1;
        const u16* srcBl0 = WloT + (size_t)r0 * FIN + c0;
        const u16* srcBl1 = WloT + (size_t)r1 * FIN + c1;

#define PSTAGE(buf, kt) do { \
        gload16(srcA0  + (kt), &lds[buf][t*8]); \
        gload16(srcA1  + (kt), &lds[buf][2048 + t*8]); \
        gload16(srcBh0 + (kt), &lds[buf][4096 + t*8]); \
        gload16(srcBh1 + (kt), &lds[buf][6144 + t*8]); \
        gload16(srcBl0 + (kt), &lds[buf][8192 + t*8]); \
        gload16(srcBl1 + (kt), &lds[buf][10240 + t*8]); \
    } while (0)

        PSTAGE(0, 0);
        __syncthreads();
        int cur = 0;
        for (int ks = 0; ks < 16; ++ks) {
            if (ks < 15) {
                if (cur) PSTAGE(0, (ks + 1) * 32);
                else     PSTAGE(1, (ks + 1) * 32);
            }
            const u16* L = lds[cur];
            short8 a[4], bh[4], bl[4];
            #pragma unroll
            for (int mt = 0; mt < 4; ++mt)
                a[mt] = *(const short8*)&L[(wr*64 + mt*16 + m16)*32 + quad*8];
            #pragma unroll
            for (int nt = 0; nt < 4; ++nt) {
                bh[nt] = *(const short8*)&L[4096 + (wc*64 + nt*16 + m16)*32 + quad*8];
                bl[nt] = *(const short8*)&L[8192 + (wc*64 + nt*16 + m16)*32 + quad*8];
            }
            #pragma unroll
            for (int mt = 0; mt < 4; ++mt)
                #pragma unroll
                for (int nt = 0; nt < 4; ++nt) {
                    acc[mt][nt] = __builtin_amdgcn_mfma_f32_16x16x32_bf16(a[mt], bh[nt], acc[mt][nt], 0,0,0);
                    acc[mt][nt] = __builtin_amdgcn_mfma_f32_16x16x32_bf16(a[mt], bl[nt], acc[mt][nt], 0,0,0);
                }
            __syncthreads();
            cur ^= 1;
        }
#undef PSTAGE
    }

    #pragma unroll
    for (int nt = 0; nt < 4; ++nt) {
        int col = wc*64 + nt*16 + m16;
        float bias = bpf[col];
        #pragma unroll
        for (int mt = 0; mt < 4; ++mt) {
            int orow0 = blockRow + wr*64 + mt*16 + quad*4;
            #pragma unroll
            for (int r = 0; r < 4; ++r) {
                int orow = orow0 + r;
                if (orow < NN) xpb[(size_t)orow*HIDDEN + col] = f2b_rne(acc[mt][nt][r] + bias);
            }
        }
    }
}

// ================= Fused: attcoef (blocks 0..1562)  ||  scatterA (blocks 1563..1808)
// scatterA: LDS-binned radix pass — histogram, scan, place into LDS bin buffer
// (scattered writes stay in LDS), then per-bucket COALESCED burst copy to the
// fixed 8192-slot global segments. One global atomic per (block,bucket).
__global__ __launch_bounds__(256) void k_fused1(
    const u16* __restrict__ xpb, const float* __restrict__ watt,
    float* __restrict__ o_as0, float* __restrict__ o_ad0,
    float* __restrict__ o_as1, float* __restrict__ o_ad1,
    const int* __restrict__ ei0, const int* __restrict__ ei1,
    int* __restrict__ curA, u32* __restrict__ tmp0, u32* __restrict__ tmp1)
{
    __shared__ u32 ebuf[EPB];        // 32 KB bin buffer (scatterA) / unused (attcoef)
    __shared__ int shA[256];         // attcoef: s0/d0 | scatterA: hist
    __shared__ int shB[256];         // attcoef: s1/d1 | scatterA: scan space
    __shared__ int shC[256];         // scatterA: place counters
    __shared__ int shD[256];         // scatterA: global segment bases
    const int t = threadIdx.x;
    const int bid = blockIdx.x;

    if (bid < ATTBLK) {
        // ---- attcoef ----
        float* s0 = (float*)shA;
        float* d0 = s0 + 128;
        float* s1 = (float*)shB;
        float* d1 = s1 + 128;
        if (t < 128) { s0[t]=watt[t]; d0[t]=watt[128+t]; s1[t]=watt[256+t]; d1[t]=watt[384+t]; }
        __syncthreads();
        int tid = bid*256 + t;               // n*8 + h
        if (tid >= NN*NH) return;
        int h = tid & 7;
        const u32* px = (const u32*)(xpb + (size_t)tid * DH);
        float xv[16];
        #pragma unroll
        for (int i=0;i<8;++i){ u32 v=px[i]; xv[i*2]=b2f((u16)(v&0xFFFF)); xv[i*2+1]=b2f((u16)(v>>16)); }
        float r0=0.f,r1=0.f,r2=0.f,r3=0.f;
        #pragma unroll
        for (int d=0; d<16; ++d) {
            float xvd = xv[d];
            r0 += xvd*s0[h*16+d]; r1 += xvd*d0[h*16+d];
            r2 += xvd*s1[h*16+d]; r3 += xvd*d1[h*16+d];
        }
        o_as0[tid]=r0; o_ad0[tid]=r1; o_as1[tid]=r2; o_ad1[tid]=r3;
    } else {
        // ---- scatterA (LDS-binned, coalesced flush) ----
        int r = bid - ATTBLK;
        const int mp = (r >= NBLKA) ? 1 : 0;
        const int bx = r - mp*NBLKA;
        const int* ei = mp ? ei1 : ei0;
        u32* tmp = mp ? tmp1 : tmp0;
        const int e0 = bx * EPB;
        const int wid = t >> 6, lane = t & 63;

        shA[t] = 0;                              // hist
        __syncthreads();
        #pragma unroll
        for (int i = 0; i < EPB/256; ++i) {
            int idx = e0 + i*256 + t;
            if (idx < EE) atomicAdd(&shA[ei[EE + idx] >> 8], 1);
        }
        __syncthreads();
        int v = shA[t];
        shB[t] = v;
        __syncthreads();
        for (int off = 1; off < 256; off <<= 1) {
            int u = (t >= off) ? shB[t - off] : 0;
            __syncthreads();
            shB[t] += u;
            __syncthreads();
        }
        int excl = shB[t] - v;                   // local bin start in ebuf
        shB[t] = excl;                           // keep exclusive offsets
        shC[t] = 0;                              // place counters
        // reserve global runs (one atomic per non-empty bucket)
        shD[t] = (t < NBUCK && v) ? atomicAdd(&curA[(mp*256 + t)*16], v) : 0;
        __syncthreads();
        #pragma unroll
        for (int i = 0; i < EPB/256; ++i) {
            int idx = e0 + i*256 + t;
            if (idx < EE) {
                int s = ei[idx], d = ei[EE + idx];
                int b = d >> 8;
                int pos = shB[b] + atomicAdd(&shC[b], 1);
                ebuf[pos] = (u32)(((d & 255) << 16) | s);
            }
        }
        __syncthreads();
        // coalesced flush: wave per bucket, contiguous run copy
        for (int b = wid; b < NBUCK; b += 4) {
            int h = shA[b];
            if (!h) continue;
            int lb = shB[b];
            u32 gb = ((u32)b << 13) + (u32)shD[b];
            for (int k = lane; k < h; k += 64)
                tmp[gb + k] = ebuf[lb + k];
        }
    }
}

// ================= Scatter pass B: per-bucket count+scan; place into LDS staging,
// then COALESCED linear copy to global srt (u16). Edge order identical to prior. ====
__global__ __launch_bounds__(256) void k_scatterB(
    const u32* __restrict__ tmp0, const u32* __restrict__ tmp1,
    const int* __restrict__ bcap,
    int* __restrict__ ns0, int* __restrict__ ns1,
    int* __restrict__ nc0, int* __restrict__ nc1,
    u16* __restrict__ srt0, u16* __restrict__ srt1)
{
    const int b = blockIdx.x;
    const int mp = blockIdx.y;
    const u32* tmp = mp ? tmp1 : tmp0;
    int* nstart = mp ? ns1 : ns0;
    int* ncnt   = mp ? nc1 : nc0;
    u16* srt    = mp ? srt1 : srt0;
    const int cntb = bcap[(mp*256 + b)*16];
    const int segbase = b << 13;
    __shared__ u16 sl[EPB];          // 16 KB sorted staging
    __shared__ int lcnt[256];
    __shared__ int loff[256];
    const int t = threadIdx.x;
    lcnt[t] = 0;
    __syncthreads();
    for (int i = t; i < cntb; i += 256)
        atomicAdd(&lcnt[tmp[segbase + i] >> 16], 1);
    __syncthreads();
    int v = lcnt[t];
    loff[t] = v;
    __syncthreads();
    for (int off = 1; off < 256; off <<= 1) {
        int u = (t >= off) ? loff[t - off] : 0;
        __syncthreads();
        loff[t] += u;
        __syncthreads();
    }
    int excl = loff[t] - v;
    int node = (b << 8) + t;
    if (node < NN) { nstart[node] = segbase + excl; ncnt[node] = v; }
    __syncthreads();
    loff[t] = excl;
    lcnt[t] = 0;
    __syncthreads();
    for (int i = t; i < cntb; i += 256) {
        u32 p = tmp[segbase + i];
        int local = p >> 16;
        int pos = loff[local] + atomicAdd(&lcnt[local], 1);
        sl[pos] = (u16)(p & 0xFFFFu);       // scattered write stays in LDS
    }
    __syncthreads();
    for (int i = t; i < cntb; i += 256)      // coalesced global write
        srt[segbase + i] = sl[i];
}

// ================= Gather (round-4 v2, srt as u16): 8 edges/iter; weights 8x8
// (edge x head) in one shot, redistributed via ds_bpermute; row bases via
// readlane->SGPR so row loads have zero per-edge VALU address math. =============
__global__ __launch_bounds__(256) void k_gather(
    const u16* __restrict__ srt0, const u16* __restrict__ srt1,
    const int* __restrict__ ns0, const int* __restrict__ ns1,
    const int* __restrict__ nc0, const int* __restrict__ nc1,
    const float* __restrict__ as0, const float* __restrict__ ad0,
    const float* __restrict__ as1, const float* __restrict__ ad1,
    const u16* __restrict__ xpb, u16* __restrict__ obf0, u16* __restrict__ obf1)
{
    const int t = threadIdx.x;
    const int wid = blockIdx.x*4 + (t >> 6);
    if (wid >= NN) return;
    const int lane = t & 63;
    const int hc = lane & 7;        // head in weight-compute phase
    const int eg = lane >> 3;       // edge slot in chunk (weight phase)
    const int mp = blockIdx.y;
    const u16*  srt  = mp ? srt1  : srt0;
    const int*  nstart = mp ? ns1 : ns0;
    const int*  ncnt   = mp ? nc1 : nc0;
    const float* asr = mp ? as1 : as0;
    const float* ads = mp ? ad1 : ad0;
    u16* obf = mp ? obf1 : obf0;
    const u32* xw = (const u32*)xpb;     // 64 u32 per row

    const int b = nstart[wid], e = b + ncnt[wid];
    const float adv = ads[wid*NH + hc];          // dst coefficient, head hc
    const int bp = (lane >> 3) << 2;             // bpermute base addr: h_out = lane>>3
    float accx = 0.f, accy = 0.f, den = 0.f;

    for (int i = b; i < e; i += 8) {
        int il = i + eg;
        int ilc = il < e ? il : e - 1;           // clamp for safe loads
        int s = srt[ilc];                        // 8 distinct edges, coalesced

        u32 rv0, rv1, rv2, rv3, rv4, rv5, rv6, rv7;
        {
            const u32* r0p = xw + ((size_t)(u32)__builtin_amdgcn_readlane(s, 0)  << 6);
            const u32* r1p = xw + ((size_t)(u32)__builtin_amdgcn_readlane(s, 8)  << 6);
            const u32* r2p = xw + ((size_t)(u32)__builtin_amdgcn_readlane(s, 16) << 6);
            const u32* r3p = xw + ((size_t)(u32)__builtin_amdgcn_readlane(s, 24) << 6);
            const u32* r4p = xw + ((size_t)(u32)__builtin_amdgcn_readlane(s, 32) << 6);
            const u32* r5p = xw + ((size_t)(u32)__builtin_amdgcn_readlane(s, 40) << 6);
            const u32* r6p = xw + ((size_t)(u32)__builtin_amdgcn_readlane(s, 48) << 6);
            const u32* r7p = xw + ((size_t)(u32)__builtin_amdgcn_readlane(s, 56) << 6);
            rv0 = r0p[lane]; rv1 = r1p[lane]; rv2 = r2p[lane]; rv3 = r3p[lane];
            rv4 = r4p[lane]; rv5 = r5p[lane]; rv6 = r6p[lane]; rv7 = r7p[lane];
        }

        float av = asr[s*NH + hc] + adv;
        av = fmaxf(av, 0.2f*av);                 // leaky_relu, slope<1
        float w = (il < e) ? __expf(av) : 0.f;   // mask invalid edges
        int wi = __float_as_int(w);

        #pragma unroll
        for (int k2 = 0; k2 < 8; ++k2) {
            float wk = __int_as_float(__builtin_amdgcn_ds_bpermute(bp + k2*32, wi));
            u32 v = (k2==0)?rv0:(k2==1)?rv1:(k2==2)?rv2:(k2==3)?rv3:
                    (k2==4)?rv4:(k2==5)?rv5:(k2==6)?rv6:rv7;
            accx = fmaf(wk, b2f((u16)(v & 0xFFFF)), accx);
            accy = fmaf(wk, b2f((u16)(v >> 16)), accy);
            den += wk;
        }
    }
    float inv = 1.f / (den + 1e-16f);
    u32 lo = f2b_rne(accx*inv), hi = f2b_rne(accy*inv);
    ((u32*)obf)[(size_t)wid*64 + lane] = (hi << 16) | lo;
}

// ================= Semantic scores via MFMA (bf16 obf direct A-operand) =============
__global__ __launch_bounds__(256) void k_semantic(
    const u16* __restrict__ obf0, const u16* __restrict__ obf1,
    const u16* __restrict__ WkThi, const float* __restrict__ bkf,
    const float* __restrict__ qf, float* __restrict__ scores)
{
    const int t = threadIdx.x;
    const int lane = t & 63;
    const int w = t >> 6;
    const int m16 = lane & 15;
    const int quad = lane >> 4;
    const int mp = blockIdx.y;
    const u16* om = mp ? obf1 : obf0;
    const int tile = blockIdx.x*4 + w;

    float partial = 0.f;
    if (tile < NN/16) {
        int row = tile*16 + m16;
        f32x4 acc[8];
        #pragma unroll
        for (int i=0;i<8;++i) acc[i] = (f32x4)(0.f);

        for (int kt = 0; kt < HIDDEN; kt += 32) {
            int kbase = kt + quad*8;
            short8 a = *(const short8*)(om + (size_t)row*HIDDEN + kbase);
            #pragma unroll
            for (int j=0;j<8;++j) a[j] = ((u16)a[j] & 0x8000u) ? (short)0 : a[j];  // relu in bf16
            #pragma unroll
            for (int nt = 0; nt < 8; ++nt) {
                int n = nt*16 + m16;
                short8 bhi = *(const short8*)(WkThi + (size_t)n*HIDDEN + kbase);
                acc[nt] = __builtin_amdgcn_mfma_f32_16x16x32_bf16(a, bhi, acc[nt], 0,0,0);
            }
        }
        #pragma unroll
        for (int nt=0; nt<8; ++nt) {
            int col = nt*16 + m16;
            float bkv = bkf[col], qv = qf[col];
            #pragma unroll
            for (int r=0;r<4;++r) {
                float xx = acc[nt][r] + bkv;
                xx = fminf(fmaxf(xx, -10.f), 10.f);
                float tex = __expf(2.f*xx);
                partial += qv * ((tex - 1.f) / (tex + 1.f));
            }
        }
    }
    __shared__ float red[256];
    red[t] = partial;
    __syncthreads();
    for (int s2 = 128; s2 > 0; s2 >>= 1) {
        if (t < s2) red[t] += red[t + s2];
        __syncthreads();
    }
    if (t == 0) unsafeAtomicAdd(&scores[mp], red[0]);
}

// ================= Final head (beta computed inline from scores) ====================
__global__ __launch_bounds__(256) void k_final(
    const u16* __restrict__ obf0, const u16* __restrict__ obf1,
    const float* __restrict__ scores, const float* __restrict__ Wlf,
    const float* __restrict__ blf, const int* __restrict__ flag,
    void* __restrict__ outv)
{
    __shared__ float fus[16*128];
    __shared__ float WlL[384];
    __shared__ float blL[3];
    const int t = threadIdx.x;
    for (int i = t; i < 384; i += 256) WlL[i] = Wlf[i];
    if (t < 3) blL[t] = blf[t];
    float sc0 = scores[0] / (float)NN;
    float sc1 = scores[1] / (float)NN;
    float m = fmaxf(sc0, sc1);
    float e0 = __expf(sc0-m), e1 = __expf(sc1-m);
    float binv = 1.f/(e0+e1);
    float b0 = e0*binv, b1 = e1*binv;

    const u32* o0w = (const u32*)obf0;
    const u32* o1w = (const u32*)obf1;
    size_t base = (size_t)blockIdx.x * 16 * 64;   // u32 units
    #pragma unroll
    for (int i=0;i<4;++i) {
        int j = t + i*256;                         // 0..1023
        u32 v0 = o0w[base + j];
        u32 v1 = o1w[base + j];
        float l0 = fmaxf(b2f((u16)(v0&0xFFFF)),0.f), h0 = fmaxf(b2f((u16)(v0>>16)),0.f);
        float l1 = fmaxf(b2f((u16)(v1&0xFFFF)),0.f), h1 = fmaxf(b2f((u16)(v1>>16)),0.f);
        int row = j >> 6, cp = j & 63;
        fus[row*128 + cp*2]     = b0*l0 + b1*l1;
        fus[row*128 + cp*2 + 1] = b0*h0 + b1*h1;
    }
    __syncthreads();
    if (t < 48) {
        int node = t / 3, c = t % 3;
        float acc = blL[c];
        const float* fr = &fus[node*128];
        #pragma unroll 16
        for (int k=0;k<128;++k) acc += fr[k]*WlL[k*3+c];
        size_t oi = (size_t)(blockIdx.x*16 + node)*NOUT + c;
        if (flag[0]) ((float*)outv)[oi] = acc;
        else         ((__hip_bfloat16*)outv)[oi] = __float2bfloat16(acc);
    }
}

extern "C" void kernel_launch(void* const* d_in, const int* in_sizes, int n_in,
                              void* d_out, int out_size, void* d_ws, size_t ws_size,
                              hipStream_t stream)
{
    const void* x   = d_in[0];
    const int* ei0  = (const int*)d_in[1];
    const int* ei1  = (const int*)d_in[2];

    float* ws = (float*)d_ws;
    u16*   xpb     = (u16*)ws;                  // 3,200,000 f
    float* a_src0  = ws +  3200000;             // 400,000 each
    float* a_dst0  = ws +  3600000;
    float* a_src1  = ws +  4000000;
    float* a_dst1  = ws +  4400000;
    u16*   obf0    = (u16*)(ws + 4800000);      // 3,200,000 f
    u16*   obf1    = (u16*)(ws + 8000000);      // 3,200,000 f
    u16*   srt0    = (u16*)(ws + 11200000);     // 1,605,632 u16 (padded segments)
    u16*   srt1    = (u16*)(ws + 12810000);
    u32*   tmp0    = (u32*)(ws + 14420000);     // 1,605,632 packed u32
    u32*   tmp1    = (u32*)(ws + 16030000);
    int*   nstart0 = (int*)(ws + 17640000);     // 50,000 each
    int*   nstart1 = (int*)(ws + 17690000);
    int*   ncnt0   = (int*)(ws + 17740000);
    int*   ncnt1   = (int*)(ws + 17790000);
    float* scores  = ws + 17840000;             // 2
    int*   flag    = (int*)(ws + 17840004);
    float* wconv   = ws + 17840008;             // 83,203 (only small-weight regions used)
    int*   curA    = (int*)(ws + 17923216);     // 8,192 ints (bucket counters, 64B-padded)
    u16*   WhiT    = (u16*)(ws + 17931408);     // 65,536 u16
    u16*   WloT    = (u16*)(ws + 17964176);     // 65,536 u16
    u16*   WkThi   = (u16*)(ws + 17996944);     // 16,384 u16
    // end ~ 18,005,136 floats ~ 72 MB

    k_prep<<<353, 256, 0, stream>>>(
        x, d_in[3], d_in[9], d_in[4], d_in[5], d_in[6], d_in[7], d_in[8],
        d_in[10], d_in[11], d_in[12], d_in[13],
        flag, scores, curA, wconv, WhiT, WloT, WkThi);

    k_projm<<<(NN+127)/128, 256, 0, stream>>>(x, WhiT, WloT, wconv + W_BP, flag, xpb);

    k_fused1<<<ATTBLK + 2*NBLKA, 256, 0, stream>>>(
        xpb, wconv + W_AS0, a_src0, a_dst0, a_src1, a_dst1,
        ei0, ei1, curA, tmp0, tmp1);

    k_scatterB<<<dim3(NBUCK,2), 256, 0, stream>>>(
        tmp0, tmp1, curA, nstart0, nstart1, ncnt0, ncnt1, srt0, srt1);

    k_gather<<<dim3((NN + 3)/4, 2), 256, 0, stream>>>(
        srt0, srt1, nstart0, nstart1, ncnt0, ncnt1,
        a_src0, a_dst0, a_src1, a_dst1, xpb, obf0, obf1);

    k_semantic<<<dim3((NN/16 + 3)/4, 2), 256, 0, stream>>>(
        obf0, obf1, WkThi, wconv + W_BK, wconv + W_Q, scores);

    k_final<<<NN/16, 256, 0, stream>>>(obf0, obf1, scores, wconv + W_WL, wconv + W_BL,
                                       flag, d_out);
}

// Round 10
// 389.301 us; speedup vs baseline: 1.1004x; 1.0177x over previous
//
#include <hip/hip_runtime.h>
#include <hip/hip_bf16.h>

#define NN 50000
#define EE 1000000
#define FIN 512
#define HIDDEN 128
#define NH 8
#define DH 16
#define NOUT 3
#define NBUCK 196   // ceil(NN/256) coarse dst buckets
#define EPB 8192    // edges per block in scatterA
#define NBLKA ((EE + EPB - 1) / EPB)   // 123
#define PROJBLK ((NN + 127) / 128)     // 391
#define ATTBLK ((NN*NH + 255) / 256)   // 1563

typedef unsigned short u16;
typedef unsigned int u32;
typedef __attribute__((ext_vector_type(8))) short short8;
typedef __attribute__((ext_vector_type(4))) float f32x4;

__device__ __forceinline__ float b2f(u16 b) { return __uint_as_float(((u32)b) << 16); }
__device__ __forceinline__ u16 f2b(float f) { return (u16)(__float_as_uint(f) >> 16); }
__device__ __forceinline__ u16 f2b_rne(float f) {
    u32 u = __float_as_uint(f);
    return (u16)((u + 0x7FFFu + ((u >> 16) & 1u)) >> 16);
}

__device__ __forceinline__ void gload16(const u16* g, u16* l) {
    __builtin_amdgcn_global_load_lds(
        (const __attribute__((address_space(1))) unsigned int*)(g),
        (__attribute__((address_space(3))) unsigned int*)(l), 16, 0, 0);
}

// Converted-weight layout (fp32), offsets within wconv:
#define W_BP   65536
#define W_AS0  65664
#define W_BK   82560
#define W_Q    82688
#define W_WL   82816
#define W_BL   83200

// ================= k_prep: dtype detect + weight convert + W^T prep + zeroing =====
__global__ __launch_bounds__(256) void k_prep(
    const void* __restrict__ x, const void* __restrict__ Wp, const void* __restrict__ Wk,
    const void* bp, const void* as0, const void* ad0, const void* as1, const void* ad1,
    const void* bk, const void* q, const void* Wl, const void* bl,
    int* __restrict__ flag, float* __restrict__ scores, int* __restrict__ curA,
    float* __restrict__ wconv, u16* __restrict__ WhiT, u16* __restrict__ WloT,
    u16* __restrict__ WkThi)
{
    const int t = threadIdx.x;
    const int bid = blockIdx.x;

    const u16* xb = (const u16*)x;
    {
        float v = b2f(xb[((t*16 + (bid & 15))*131)*2]);
        float a = fabsf(v);
        int insane = ((a == 0.0f) || (a >= 1e-8f && a <= 1e4f)) ? 0 : 1;
        __shared__ int red[256];
        red[t] = insane;
        __syncthreads();
        for (int s = 128; s > 0; s >>= 1) { if (t < s) red[t] += red[t+s]; __syncthreads(); }
        const int f = (red[0] > 64) ? 1 : 0;
        if (bid == 0 && t == 0) { flag[0] = f; scores[0] = 0.f; scores[1] = 0.f; }

        if (bid < 256) {
            int idx = bid*256 + t;               // Wp row-major [k][n]
            float w = f ? ((const float*)Wp)[idx] : b2f(((const u16*)Wp)[idx]);
            int k = idx >> 7, n = idx & 127;
            u32 hb = __float_as_uint(w) & 0xFFFF0000u;
            WhiT[(size_t)n*FIN + k] = (u16)(hb >> 16);
            WloT[(size_t)n*FIN + k] = f2b(w - __uint_as_float(hb));
        } else if (bid < 320) {
            int i = (bid-256)*256 + t;           // Wk row-major [k][h]
            float w = f ? ((const float*)Wk)[i] : b2f(((const u16*)Wk)[i]);
            int k = i >> 7, h = i & 127;
            WkThi[(size_t)h*HIDDEN + k] = f2b_rne(w);
        } else if (bid == 320) {
            #pragma unroll
            for (int j = 0; j < 6; ++j) {
                int i = j*256 + t;
                if (i < 1283) {
                    const void* src; int off; int dst;
                    if (i < 640) {
                        dst = W_BP + i;
                        if (i < 128)      { src = bp;  off = i; }
                        else if (i < 256) { src = as0; off = i-128; }
                        else if (i < 384) { src = ad0; off = i-256; }
                        else if (i < 512) { src = as1; off = i-384; }
                        else              { src = ad1; off = i-512; }
                    } else if (i < 896) {
                        dst = W_BK + (i-640);
                        if (i < 768) { src = bk; off = i-640; }
                        else         { src = q;  off = i-768; }
                    } else {
                        dst = W_WL + (i-896);
                        if (i < 1280) { src = Wl; off = i-896; }
                        else          { src = bl; off = i-1280; }
                    }
                    wconv[dst] = f ? ((const float*)src)[off] : b2f(((const u16*)src)[off]);
                }
            }
        } else {
            int i = (bid-321)*256 + t;           // zero curA (bucket counters)
            if (i < 8192) curA[i] = 0;
        }
    }
}

// ================= Kernel 2: projm (blocks 0..390)  ||  scatterA (391..636) =======
// projm: 128x128 tile LDS MFMA GEMM (both dtype paths).
// scatterA: LDS-binned radix pass (proven round-7 body, incl. Hillis-Steele scan)
// into fixed 8192-slot global bucket segments, coalesced flush. Independent of
// projm -> hides under it. Aliases projm's LDS allocation.
__global__ __launch_bounds__(256) void k_projm_sa(
    const void* __restrict__ xv, const u16* __restrict__ WhiT,
    const u16* __restrict__ WloT, const float* __restrict__ bpf,
    const int* __restrict__ flag, u16* __restrict__ xpb,
    const int* __restrict__ ei0, const int* __restrict__ ei1,
    int* __restrict__ curA, u32* __restrict__ tmp0, u32* __restrict__ tmp1)
{
    __shared__ u16 lds[2][16384];             // 64 KB (projm); scatterA aliases 36 KB
    const int t = threadIdx.x;
    const int lane = t & 63;
    const int wid = t >> 6;

    if (blockIdx.x >= PROJBLK) {
        // ---------------- scatterA (proven round-7 body) ----------------
        int r = blockIdx.x - PROJBLK;
        const int mp = (r >= NBLKA) ? 1 : 0;
        const int bx = r - mp*NBLKA;
        const int* ei = mp ? ei1 : ei0;
        u32* tmp = mp ? tmp1 : tmp0;
        const int e0 = bx * EPB;
        u32* ebuf = (u32*)&lds[0][0];            // 8192 u32 = 32 KB
        int* shA  = (int*)(&lds[0][0] + 16384);  // hist (256)
        int* shB  = shA + 256;                   // scan space -> excl offsets
        int* shC  = shB + 256;                   // place counters
        int* shD  = shC + 256;                   // global segment bases

        shA[t] = 0;
        __syncthreads();
        #pragma unroll
        for (int i = 0; i < EPB/256; ++i) {
            int idx = e0 + i*256 + t;
            if (idx < EE) atomicAdd(&shA[ei[EE + idx] >> 8], 1);
        }
        __syncthreads();
        int v = shA[t];
        shB[t] = v;
        __syncthreads();
        for (int off = 1; off < 256; off <<= 1) {
            int u = (t >= off) ? shB[t - off] : 0;
            __syncthreads();
            shB[t] += u;
            __syncthreads();
        }
        int excl = shB[t] - v;                   // local bin start in ebuf
        __syncthreads();
        shB[t] = excl;
        shC[t] = 0;
        shD[t] = (t < NBUCK && v) ? atomicAdd(&curA[(mp*256 + t)*16], v) : 0;
        __syncthreads();
        #pragma unroll
        for (int i = 0; i < EPB/256; ++i) {
            int idx = e0 + i*256 + t;
            if (idx < EE) {
                int s = ei[idx], d = ei[EE + idx];
                int b = d >> 8;
                int pos = shB[b] + atomicAdd(&shC[b], 1);
                ebuf[pos] = (u32)(((d & 255) << 16) | s);
            }
        }
        __syncthreads();
        for (int b = wid; b < NBUCK; b += 4) {   // coalesced flush, wave per bucket
            int h = shA[b];
            if (!h) continue;
            int lb = shB[b];
            u32 gb = ((u32)b << 13) + (u32)shD[b];
            for (int k = lane; k < h; k += 64)
                tmp[gb + k] = ebuf[lb + k];
        }
        return;
    }

    // ---------------- projm ----------------
    const int m16 = lane & 15;
    const int quad = lane >> 4;
    const int wr = wid >> 1, wc = wid & 1;
    const int blockRow = blockIdx.x * 128;

    f32x4 acc[4][4];
    #pragma unroll
    for (int i = 0; i < 4; ++i)
        #pragma unroll
        for (int j = 0; j < 4; ++j) acc[i][j] = (f32x4)(0.f);

    if (flag[0]) {
        // ---------- fp32-input path ----------
        const float* xf = (const float*)xv;
        const int srow = t >> 1;
        const int shalf = t & 1;
        int gxrow = blockRow + srow; if (gxrow >= NN) gxrow = NN - 1;
        const float* xr = xf + (size_t)gxrow * FIN + shalf * 16;
        const int ssw = (srow >> 1) & 3;
        const int aw0 = srow*32 + ((shalf*2)     ^ ssw) * 8;
        const int aw1 = srow*32 + ((shalf*2 + 1) ^ ssw) * 8;

        int bp0 = t, bp1 = t + 256;
        int br0 = bp0 >> 2, br1 = bp1 >> 2;
        int bc0 = (bp0 & 3) ^ ((br0 >> 1) & 3);
        int bc1 = (bp1 & 3) ^ ((br1 >> 1) & 3);
        const u16* srcBh0 = WhiT + (size_t)br0 * FIN + bc0 * 8;
        const u16* srcBh1 = WhiT + (size_t)br1 * FIN + bc1 * 8;
        const u16* srcBl0 = WloT + (size_t)br0 * FIN + bc0 * 8;
        const u16* srcBl1 = WloT + (size_t)br1 * FIN + bc1 * 8;
        const int dB0 = bp0 * 8, dB1 = bp1 * 8;

        int aoff[4], boff[4];
        #pragma unroll
        for (int mt = 0; mt < 4; ++mt) {
            int rr = wr*64 + mt*16 + m16;
            aoff[mt] = rr*32 + ((quad ^ ((rr >> 1) & 3)) << 3);
        }
        #pragma unroll
        for (int nt = 0; nt < 4; ++nt) {
            int rr = wc*64 + nt*16 + m16;
            boff[nt] = rr*32 + ((quad ^ ((rr >> 1) & 3)) << 3);
        }

        u16* Lc = lds[0];
        u16* Ln = lds[1];
        {
            float4 v0 = *(const float4*)(xr);
            float4 v1 = *(const float4*)(xr + 4);
            float4 v2 = *(const float4*)(xr + 8);
            float4 v3 = *(const float4*)(xr + 12);
            gload16(srcBh0, Lc + 8192  + dB0);
            gload16(srcBh1, Lc + 8192  + dB1);
            gload16(srcBl0, Lc + 12288 + dB0);
            gload16(srcBl1, Lc + 12288 + dB1);
            float xs[16] = {v0.x,v0.y,v0.z,v0.w, v1.x,v1.y,v1.z,v1.w,
                            v2.x,v2.y,v2.z,v2.w, v3.x,v3.y,v3.z,v3.w};
            short8 h0, h1, l0, l1;
            #pragma unroll
            for (int j = 0; j < 8; ++j) {
                u32 u = __float_as_uint(xs[j]);   u32 hb = u & 0xFFFF0000u;
                h0[j] = (short)(hb >> 16); l0[j] = (short)f2b(xs[j] - __uint_as_float(hb));
                u32 u2 = __float_as_uint(xs[8+j]); u32 hb2 = u2 & 0xFFFF0000u;
                h1[j] = (short)(hb2 >> 16); l1[j] = (short)f2b(xs[8+j] - __uint_as_float(hb2));
            }
            *(short8*)(Lc + aw0) = h0;
            *(short8*)(Lc + aw1) = h1;
            *(short8*)(Lc + 4096 + aw0) = l0;
            *(short8*)(Lc + 4096 + aw1) = l1;
        }
        __syncthreads();

        #pragma unroll 1
        for (int ks = 0; ks < 16; ++ks) {
            const int kt = (ks + 1) * 32;
            float4 v0, v1, v2, v3;
            if (ks < 15) {
                v0 = *(const float4*)(xr + kt);
                v1 = *(const float4*)(xr + kt + 4);
                v2 = *(const float4*)(xr + kt + 8);
                v3 = *(const float4*)(xr + kt + 12);
                gload16(srcBh0 + kt, Ln + 8192  + dB0);
                gload16(srcBh1 + kt, Ln + 8192  + dB1);
                gload16(srcBl0 + kt, Ln + 12288 + dB0);
                gload16(srcBl1 + kt, Ln + 12288 + dB1);
            }
            short8 bh[4], bl[4];
            #pragma unroll
            for (int nt = 0; nt < 4; ++nt) {
                bh[nt] = *(const short8*)(Lc + 8192  + boff[nt]);
                bl[nt] = *(const short8*)(Lc + 12288 + boff[nt]);
            }
            #pragma unroll
            for (int mt = 0; mt < 4; ++mt) {
                short8 ah = *(const short8*)(Lc + aoff[mt]);
                short8 al = *(const short8*)(Lc + 4096 + aoff[mt]);
                #pragma unroll
                for (int nt = 0; nt < 4; ++nt) {
                    acc[mt][nt] = __builtin_amdgcn_mfma_f32_16x16x32_bf16(ah, bh[nt], acc[mt][nt], 0,0,0);
                    acc[mt][nt] = __builtin_amdgcn_mfma_f32_16x16x32_bf16(ah, bl[nt], acc[mt][nt], 0,0,0);
                    acc[mt][nt] = __builtin_amdgcn_mfma_f32_16x16x32_bf16(al, bh[nt], acc[mt][nt], 0,0,0);
                }
            }
            if (ks < 15) {
                float xs[16] = {v0.x,v0.y,v0.z,v0.w, v1.x,v1.y,v1.z,v1.w,
                                v2.x,v2.y,v2.z,v2.w, v3.x,v3.y,v3.z,v3.w};
                short8 h0, h1, l0, l1;
                #pragma unroll
                for (int j = 0; j < 8; ++j) {
                    u32 u = __float_as_uint(xs[j]);   u32 hb = u & 0xFFFF0000u;
                    h0[j] = (short)(hb >> 16); l0[j] = (short)f2b(xs[j] - __uint_as_float(hb));
                    u32 u2 = __float_as_uint(xs[8+j]); u32 hb2 = u2 & 0xFFFF0000u;
                    h1[j] = (short)(hb2 >> 16); l1[j] = (short)f2b(xs[8+j] - __uint_as_float(hb2));
                }
                *(short8*)(Ln + aw0) = h0;
                *(short8*)(Ln + aw1) = h1;
                *(short8*)(Ln + 4096 + aw0) = l0;
                *(short8*)(Ln + 4096 + aw1) = l1;
            }
            __syncthreads();
            u16* tmp2 = Lc; Lc = Ln; Ln = tmp2;
        }
    } else {
        // ---------- bf16-input path ----------
        const u16* xb = (const u16*)xv;
        const int r0 = t >> 2,         c0 = (t & 3) * 8;
        const int r1 = (t + 256) >> 2, c1 = ((t + 256) & 3) * 8;
        int g0 = blockRow + r0; if (g0 >= NN) g0 = NN - 1;
        int g1 = blockRow + r1; if (g1 >= NN) g1 = NN - 1;
        const u16* srcA0  = xb   + (size_t)g0 * FIN + c0;
        const u16* srcA1  = xb   + (size_t)g1 * FIN + c1;
        const u16* srcBh0 = WhiT + (size_t)r0 * FIN + c0;
        const u16* srcBh1 = WhiT + (size_t)r1 * FIN + c1;
        const u16* srcBl0 = WloT + (size_t)r0 * FIN + c0;
        const u16* srcBl1 = WloT + (size_t)r1 * FIN + c1;

#define PSTAGE(buf, kt) do { \
        gload16(srcA0  + (kt), &lds[buf][t*8]); \
        gload16(srcA1  + (kt), &lds[buf][2048 + t*8]); \
        gload16(srcBh0 + (kt), &lds[buf][4096 + t*8]); \
        gload16(srcBh1 + (kt), &lds[buf][6144 + t*8]); \
        gload16(srcBl0 + (kt), &lds[buf][8192 + t*8]); \
        gload16(srcBl1 + (kt), &lds[buf][10240 + t*8]); \
    } while (0)

        PSTAGE(0, 0);
        __syncthreads();
        int cur = 0;
        for (int ks = 0; ks < 16; ++ks) {
            if (ks < 15) {
                if (cur) PSTAGE(0, (ks + 1) * 32);
                else     PSTAGE(1, (ks + 1) * 32);
            }
            const u16* L = lds[cur];
            short8 a[4], bh[4], bl[4];
            #pragma unroll
            for (int mt = 0; mt < 4; ++mt)
                a[mt] = *(const short8*)&L[(wr*64 + mt*16 + m16)*32 + quad*8];
            #pragma unroll
            for (int nt = 0; nt < 4; ++nt) {
                bh[nt] = *(const short8*)&L[4096 + (wc*64 + nt*16 + m16)*32 + quad*8];
                bl[nt] = *(const short8*)&L[8192 + (wc*64 + nt*16 + m16)*32 + quad*8];
            }
            #pragma unroll
            for (int mt = 0; mt < 4; ++mt)
                #pragma unroll
                for (int nt = 0; nt < 4; ++nt) {
                    acc[mt][nt] = __builtin_amdgcn_mfma_f32_16x16x32_bf16(a[mt], bh[nt], acc[mt][nt], 0,0,0);
                    acc[mt][nt] = __builtin_amdgcn_mfma_f32_16x16x32_bf16(a[mt], bl[nt], acc[mt][nt], 0,0,0);
                }
            __syncthreads();
            cur ^= 1;
        }
#undef PSTAGE
    }

    #pragma unroll
    for (int nt = 0; nt < 4; ++nt) {
        int col = wc*64 + nt*16 + m16;
        float bias = bpf[col];
        #pragma unroll
        for (int mt = 0; mt < 4; ++mt) {
            int orow0 = blockRow + wr*64 + mt*16 + quad*4;
            #pragma unroll
            for (int r = 0; r < 4; ++r) {
                int orow = orow0 + r;
                if (orow < NN) xpb[(size_t)orow*HIDDEN + col] = f2b_rne(acc[mt][nt][r] + bias);
            }
        }
    }
}

// ================= Kernel 3: scatterB (blocks 0..391)  ||  attcoef (392..1954) =====
// scatterB: proven round-7 body (Hillis-Steele scan, LDS staging, coalesced out).
__global__ __launch_bounds__(256) void k_att_sb(
    const u16* __restrict__ xpb, const float* __restrict__ watt,
    float* __restrict__ o_as0, float* __restrict__ o_ad0,
    float* __restrict__ o_as1, float* __restrict__ o_ad1,
    const u32* __restrict__ tmp0, const u32* __restrict__ tmp1,
    const int* __restrict__ bcap,
    int* __restrict__ ns0, int* __restrict__ ns1,
    int* __restrict__ nc0, int* __restrict__ nc1,
    u16* __restrict__ srt0, u16* __restrict__ srt1)
{
    __shared__ u16 sh3[9216];        // 18 KB: sl (16 KB) + lcnt/loff (2 KB)
    const int t = threadIdx.x;
    const int bid = blockIdx.x;

    if (bid < 2*NBUCK) {
        // ---------------- scatterB ----------------
        const int mp = (bid >= NBUCK) ? 1 : 0;
        const int b = bid - mp*NBUCK;
        const u32* tmp = mp ? tmp1 : tmp0;
        int* nstart = mp ? ns1 : ns0;
        int* ncnt   = mp ? nc1 : nc0;
        u16* srt    = mp ? srt1 : srt0;
        const int cntb = bcap[(mp*256 + b)*16];
        const int segbase = b << 13;
        u16* sl   = sh3;                         // 8192 u16
        int* lcnt = (int*)(sh3 + 8192);          // 256 int
        int* loff = lcnt + 256;                  // 256 int
        lcnt[t] = 0;
        __syncthreads();
        for (int i = t; i < cntb; i += 256)
            atomicAdd(&lcnt[tmp[segbase + i] >> 16], 1);
        __syncthreads();
        int v = lcnt[t];
        loff[t] = v;
        __syncthreads();
        for (int off = 1; off < 256; off <<= 1) {
            int u = (t >= off) ? loff[t - off] : 0;
            __syncthreads();
            loff[t] += u;
            __syncthreads();
        }
        int excl = loff[t] - v;
        int node = (b << 8) + t;
        if (node < NN) { nstart[node] = segbase + excl; ncnt[node] = v; }
        __syncthreads();
        loff[t] = excl;
        lcnt[t] = 0;
        __syncthreads();
        for (int i = t; i < cntb; i += 256) {
            u32 p = tmp[segbase + i];
            int local = p >> 16;
            int pos = loff[local] + atomicAdd(&lcnt[local], 1);
            sl[pos] = (u16)(p & 0xFFFFu);        // scattered write stays in LDS
        }
        __syncthreads();
        for (int i = t; i < cntb; i += 256)      // coalesced global write
            srt[segbase + i] = sl[i];
    } else {
        // ---------------- attcoef ----------------
        float* s0 = (float*)sh3;                 // 512 floats = 2 KB
        float* d0 = s0 + 128;
        float* s1 = s0 + 256;
        float* d1 = s0 + 384;
        if (t < 128) { s0[t]=watt[t]; d0[t]=watt[128+t]; s1[t]=watt[256+t]; d1[t]=watt[384+t]; }
        __syncthreads();
        int tid = (bid - 2*NBUCK)*256 + t;       // n*8 + h
        if (tid >= NN*NH) return;
        int h = tid & 7;
        const u32* px = (const u32*)(xpb + (size_t)tid * DH);
        float xv[16];
        #pragma unroll
        for (int i=0;i<8;++i){ u32 v=px[i]; xv[i*2]=b2f((u16)(v&0xFFFF)); xv[i*2+1]=b2f((u16)(v>>16)); }
        float r0=0.f,r1=0.f,r2=0.f,r3=0.f;
        #pragma unroll
        for (int d=0; d<16; ++d) {
            float xvd = xv[d];
            r0 += xvd*s0[h*16+d]; r1 += xvd*d0[h*16+d];
            r2 += xvd*s1[h*16+d]; r3 += xvd*d1[h*16+d];
        }
        o_as0[tid]=r0; o_ad0[tid]=r1; o_as1[tid]=r2; o_ad1[tid]=r3;
    }
}

// ================= Gather (proven round-4 v2, u16 srt) ============================
__global__ __launch_bounds__(256) void k_gather(
    const u16* __restrict__ srt0, const u16* __restrict__ srt1,
    const int* __restrict__ ns0, const int* __restrict__ ns1,
    const int* __restrict__ nc0, const int* __restrict__ nc1,
    const float* __restrict__ as0, const float* __restrict__ ad0,
    const float* __restrict__ as1, const float* __restrict__ ad1,
    const u16* __restrict__ xpb, u16* __restrict__ obf0, u16* __restrict__ obf1)
{
    const int t = threadIdx.x;
    const int wid = blockIdx.x*4 + (t >> 6);
    if (wid >= NN) return;
    const int lane = t & 63;
    const int hc = lane & 7;
    const int eg = lane >> 3;
    const int mp = blockIdx.y;
    const u16*  srt  = mp ? srt1  : srt0;
    const int*  nstart = mp ? ns1 : ns0;
    const int*  ncnt   = mp ? nc1 : nc0;
    const float* asr = mp ? as1 : as0;
    const float* ads = mp ? ad1 : ad0;
    u16* obf = mp ? obf1 : obf0;
    const u32* xw = (const u32*)xpb;

    const int b = nstart[wid], e = b + ncnt[wid];
    const float adv = ads[wid*NH + hc];
    const int bp = (lane >> 3) << 2;
    float accx = 0.f, accy = 0.f, den = 0.f;

    for (int i = b; i < e; i += 8) {
        int il = i + eg;
        int ilc = il < e ? il : e - 1;
        int s = srt[ilc];

        u32 rv0, rv1, rv2, rv3, rv4, rv5, rv6, rv7;
        {
            const u32* r0p = xw + ((size_t)(u32)__builtin_amdgcn_readlane(s, 0)  << 6);
            const u32* r1p = xw + ((size_t)(u32)__builtin_amdgcn_readlane(s, 8)  << 6);
            const u32* r2p = xw + ((size_t)(u32)__builtin_amdgcn_readlane(s, 16) << 6);
            const u32* r3p = xw + ((size_t)(u32)__builtin_amdgcn_readlane(s, 24) << 6);
            const u32* r4p = xw + ((size_t)(u32)__builtin_amdgcn_readlane(s, 32) << 6);
            const u32* r5p = xw + ((size_t)(u32)__builtin_amdgcn_readlane(s, 40) << 6);
            const u32* r6p = xw + ((size_t)(u32)__builtin_amdgcn_readlane(s, 48) << 6);
            const u32* r7p = xw + ((size_t)(u32)__builtin_amdgcn_readlane(s, 56) << 6);
            rv0 = r0p[lane]; rv1 = r1p[lane]; rv2 = r2p[lane]; rv3 = r3p[lane];
            rv4 = r4p[lane]; rv5 = r5p[lane]; rv6 = r6p[lane]; rv7 = r7p[lane];
        }

        float av = asr[s*NH + hc] + adv;
        av = fmaxf(av, 0.2f*av);
        float w = (il < e) ? __expf(av) : 0.f;
        int wi = __float_as_int(w);

        #pragma unroll
        for (int k2 = 0; k2 < 8; ++k2) {
            float wk = __int_as_float(__builtin_amdgcn_ds_bpermute(bp + k2*32, wi));
            u32 v = (k2==0)?rv0:(k2==1)?rv1:(k2==2)?rv2:(k2==3)?rv3:
                    (k2==4)?rv4:(k2==5)?rv5:(k2==6)?rv6:rv7;
            accx = fmaf(wk, b2f((u16)(v & 0xFFFF)), accx);
            accy = fmaf(wk, b2f((u16)(v >> 16)), accy);
            den += wk;
        }
    }
    float inv = 1.f / (den + 1e-16f);
    u32 lo = f2b_rne(accx*inv), hi = f2b_rne(accy*inv);
    ((u32*)obf)[(size_t)wid*64 + lane] = (hi << 16) | lo;
}

// ================= Semantic scores via MFMA =======================================
__global__ __launch_bounds__(256) void k_semantic(
    const u16* __restrict__ obf0, const u16* __restrict__ obf1,
    const u16* __restrict__ WkThi, const float* __restrict__ bkf,
    const float* __restrict__ qf, float* __restrict__ scores)
{
    const int t = threadIdx.x;
    const int lane = t & 63;
    const int w = t >> 6;
    const int m16 = lane & 15;
    const int quad = lane >> 4;
    const int mp = blockIdx.y;
    const u16* om = mp ? obf1 : obf0;
    const int tile = blockIdx.x*4 + w;

    float partial = 0.f;
    if (tile < NN/16) {
        int row = tile*16 + m16;
        f32x4 acc[8];
        #pragma unroll
        for (int i=0;i<8;++i) acc[i] = (f32x4)(0.f);

        for (int kt = 0; kt < HIDDEN; kt += 32) {
            int kbase = kt + quad*8;
            short8 a = *(const short8*)(om + (size_t)row*HIDDEN + kbase);
            #pragma unroll
            for (int j=0;j<8;++j) a[j] = ((u16)a[j] & 0x8000u) ? (short)0 : a[j];
            #pragma unroll
            for (int nt = 0; nt < 8; ++nt) {
                int n = nt*16 + m16;
                short8 bhi = *(const short8*)(WkThi + (size_t)n*HIDDEN + kbase);
                acc[nt] = __builtin_amdgcn_mfma_f32_16x16x32_bf16(a, bhi, acc[nt], 0,0,0);
            }
        }
        #pragma unroll
        for (int nt=0; nt<8; ++nt) {
            int col = nt*16 + m16;
            float bkv = bkf[col], qv = qf[col];
            #pragma unroll
            for (int r=0;r<4;++r) {
                float xx = acc[nt][r] + bkv;
                xx = fminf(fmaxf(xx, -10.f), 10.f);
                float tex = __expf(2.f*xx);
                partial += qv * ((tex - 1.f) / (tex + 1.f));
            }
        }
    }
    __shared__ float red[256];
    red[t] = partial;
    __syncthreads();
    for (int s2 = 128; s2 > 0; s2 >>= 1) {
        if (t < s2) red[t] += red[t + s2];
        __syncthreads();
    }
    if (t == 0) unsafeAtomicAdd(&scores[mp], red[0]);
}

// ================= Final head (beta inline) =======================================
__global__ __launch_bounds__(256) void k_final(
    const u16* __restrict__ obf0, const u16* __restrict__ obf1,
    const float* __restrict__ scores, const float* __restrict__ Wlf,
    const float* __restrict__ blf, const int* __restrict__ flag,
    void* __restrict__ outv)
{
    __shared__ float fus[16*128];
    __shared__ float WlL[384];
    __shared__ float blL[3];
    const int t = threadIdx.x;
    for (int i = t; i < 384; i += 256) WlL[i] = Wlf[i];
    if (t < 3) blL[t] = blf[t];
    float sc0 = scores[0] / (float)NN;
    float sc1 = scores[1] / (float)NN;
    float m = fmaxf(sc0, sc1);
    float e0 = __expf(sc0-m), e1 = __expf(sc1-m);
    float binv = 1.f/(e0+e1);
    float b0 = e0*binv, b1 = e1*binv;

    const u32* o0w = (const u32*)obf0;
    const u32* o1w = (const u32*)obf1;
    size_t base = (size_t)blockIdx.x * 16 * 64;
    #pragma unroll
    for (int i=0;i<4;++i) {
        int j = t + i*256;
        u32 v0 = o0w[base + j];
        u32 v1 = o1w[base + j];
        float l0 = fmaxf(b2f((u16)(v0&0xFFFF)),0.f), h0 = fmaxf(b2f((u16)(v0>>16)),0.f);
        float l1 = fmaxf(b2f((u16)(v1&0xFFFF)),0.f), h1 = fmaxf(b2f((u16)(v1>>16)),0.f);
        int row = j >> 6, cp = j & 63;
        fus[row*128 + cp*2]     = b0*l0 + b1*l1;
        fus[row*128 + cp*2 + 1] = b0*h0 + b1*h1;
    }
    __syncthreads();
    if (t < 48) {
        int node = t / 3, c = t % 3;
        float acc = blL[c];
        const float* fr = &fus[node*128];
        #pragma unroll 16
        for (int k=0;k<128;++k) acc += fr[k]*WlL[k*3+c];
        size_t oi = (size_t)(blockIdx.x*16 + node)*NOUT + c;
        if (flag[0]) ((float*)outv)[oi] = acc;
        else         ((__hip_bfloat16*)outv)[oi] = __float2bfloat16(acc);
    }
}

extern "C" void kernel_launch(void* const* d_in, const int* in_sizes, int n_in,
                              void* d_out, int out_size, void* d_ws, size_t ws_size,
                              hipStream_t stream)
{
    const void* x   = d_in[0];
    const int* ei0  = (const int*)d_in[1];
    const int* ei1  = (const int*)d_in[2];

    float* ws = (float*)d_ws;
    u16*   xpb     = (u16*)ws;                  // 3,200,000 f
    float* a_src0  = ws +  3200000;
    float* a_dst0  = ws +  3600000;
    float* a_src1  = ws +  4000000;
    float* a_dst1  = ws +  4400000;
    u16*   obf0    = (u16*)(ws + 4800000);      // 3,200,000 f
    u16*   obf1    = (u16*)(ws + 8000000);      // 3,200,000 f
    u16*   srt0    = (u16*)(ws + 11200000);     // 1,605,632 u16 (padded segments)
    u16*   srt1    = (u16*)(ws + 12810000);
    u32*   tmp0    = (u32*)(ws + 14420000);     // 1,605,632 packed u32
    u32*   tmp1    = (u32*)(ws + 16030000);
    int*   nstart0 = (int*)(ws + 17640000);
    int*   nstart1 = (int*)(ws + 17690000);
    int*   ncnt0   = (int*)(ws + 17740000);
    int*   ncnt1   = (int*)(ws + 17790000);
    float* scores  = ws + 17840000;             // 2
    int*   flag    = (int*)(ws + 17840004);
    float* wconv   = ws + 17840008;             // 83,203
    int*   curA    = (int*)(ws + 17923216);     // 8,192 ints (bucket counters)
    u16*   WhiT    = (u16*)(ws + 17931408);     // 65,536 u16
    u16*   WloT    = (u16*)(ws + 17964176);     // 65,536 u16
    u16*   WkThi   = (u16*)(ws + 17996944);     // 16,384 u16

    // 6 launches; scatterA hidden under projm, scatterB overlapped with attcoef.
    k_prep<<<353, 256, 0, stream>>>(
        x, d_in[3], d_in[9], d_in[4], d_in[5], d_in[6], d_in[7], d_in[8],
        d_in[10], d_in[11], d_in[12], d_in[13],
        flag, scores, curA, wconv, WhiT, WloT, WkThi);

    k_projm_sa<<<PROJBLK + 2*NBLKA, 256, 0, stream>>>(
        x, WhiT, WloT, wconv + W_BP, flag, xpb,
        ei0, ei1, curA, tmp0, tmp1);

    k_att_sb<<<2*NBUCK + ATTBLK, 256, 0, stream>>>(
        xpb, wconv + W_AS0, a_src0, a_dst0, a_src1, a_dst1,
        tmp0, tmp1, curA, nstart0, nstart1, ncnt0, ncnt1, srt0, srt1);

    k_gather<<<dim3((NN + 3)/4, 2), 256, 0, stream>>>(
        srt0, srt1, nstart0, nstart1, ncnt0, ncnt1,
        a_src0, a_dst0, a_src1, a_dst1, xpb, obf0, obf1);

    k_semantic<<<dim3((NN/16 + 3)/4, 2), 256, 0, stream>>>(
        obf0, obf1, WkThi, wconv + W_BK, wconv + W_Q, scores);

    k_final<<<NN/16, 256, 0, stream>>>(obf0, obf1, scores, wconv + W_WL, wconv + W_BL,
                                       flag, d_out);
}